// Round 17
// baseline (1138.042 us; speedup 1.0000x reference)
//
#include <hip/hip_runtime.h>
#include <math.h>

#define HH 192
#define WW 192
#define HWQ 36864          // 192*192
#define NB 2
#define NT 3
#define CDIM 96

typedef __attribute__((ext_vector_type(8))) short bf16x8;
typedef __attribute__((ext_vector_type(4))) float f32x4;

// ---------- helpers ----------
__device__ __forceinline__ float lrelu02(float v){ return v > 0.f ? v : 0.2f*v; }

__device__ __forceinline__ unsigned short f2bf(float f){
    unsigned u = __builtin_bit_cast(unsigned, f);
    unsigned r = (u + 0x7fff + ((u>>16)&1)) >> 16;   // RNE
    return (unsigned short)r;
}
__device__ __forceinline__ float bf2f(unsigned short u){
    unsigned v = ((unsigned)u)<<16;
    return __builtin_bit_cast(float, v);
}

// ================= layout shims (LDS transpose, coalesced both sides) =================
__global__ __launch_bounds__(256) void k_fillcatT(const float* __restrict__ F,
                                                  unsigned short* __restrict__ catA){
    __shared__ unsigned short ls[64*104];
    const int tid = threadIdx.x;
    const int p0 = blockIdx.x*64;
    const int fi = blockIdx.z;
    const int b = fi/NT, t = fi - b*NT;
    for (int i = tid; i < 6144; i += 256){
        int px = i & 63, c = i >> 6;
        ls[px*104 + c] = f2bf(F[(((size_t)b*CDIM + c)*NT + t)*HWQ + p0 + px]);
    }
    __syncthreads();
    for (int i = tid; i < 768; i += 256){
        int px = i / 12, ck = i % 12;
        *(bf16x8*)(catA + ((size_t)fi*HWQ + p0 + px)*96 + ck*8) =
            *(const bf16x8*)(ls + px*104 + ck*8);
    }
}

__global__ __launch_bounds__(256) void k_fillF0T(const float* __restrict__ F0c,
                                                 unsigned short* __restrict__ F0T){
    __shared__ unsigned short ls[64*104];
    const int tid = threadIdx.x;
    const int p0 = blockIdx.x*64;
    const int b = blockIdx.z;
    for (int i = tid; i < 6144; i += 256){
        int px = i & 63, c = i >> 6;
        ls[px*104 + c] = f2bf(F0c[((size_t)b*96 + c)*HWQ + p0 + px]);
    }
    __syncthreads();
    for (int i = tid; i < 768; i += 256){
        int px = i / 12, ck = i % 12;
        *(bf16x8*)(F0T + ((size_t)b*HWQ + p0 + px)*96 + ck*8) =
            *(const bf16x8*)(ls + px*104 + ck*8);
    }
}

__global__ __launch_bounds__(256) void k_packF0C(const float* __restrict__ F0c,
                                                 float* __restrict__ F0C){
    __shared__ float ls[64*100];
    const int tid = threadIdx.x;
    const int p0 = blockIdx.x*64;
    const int b = blockIdx.z;
    for (int i = tid; i < 6144; i += 256){
        int px = i & 63, c = i >> 6;
        ls[px*100 + c] = F0c[((size_t)b*96 + c)*HWQ + p0 + px];
    }
    __syncthreads();
    for (int i = tid; i < 1536; i += 256){
        int px = i / 24, ck = i % 24;
        *(f32x4*)(F0C + ((size_t)b*HWQ + p0 + px)*96 + ck*4) =
            *(const f32x4*)(ls + px*100 + ck*4);
    }
}

__global__ __launch_bounds__(256) void k_unpackFw(const float* __restrict__ FwC,
                                                  float* __restrict__ Fw){
    __shared__ float ls[64*100];
    const int tid = threadIdx.x;
    const int p0 = blockIdx.x*64;
    const int b = blockIdx.z;
    for (int i = tid; i < 1536; i += 256){
        int px = i / 24, ck = i % 24;
        *(f32x4*)(ls + px*100 + ck*4) =
            *(const f32x4*)(FwC + ((size_t)b*HWQ + p0 + px)*96 + ck*4);
    }
    __syncthreads();
    for (int i = tid; i < 6144; i += 256){
        int px = i & 63, c = i >> 6;
        Fw[((size_t)b*96 + c)*HWQ + p0 + px] = ls[px*100 + c];
    }
}

// FoT [fi][px][96] -> FoT2 [b][nf][t][px][12]
__global__ __launch_bounds__(256) void k_nfsplit(const unsigned short* __restrict__ FoT,
                                                 unsigned short* __restrict__ FoT2){
    __shared__ unsigned short ls[64*104];
    const int tid = threadIdx.x;
    const int p0 = blockIdx.x*64;
    const int fi = blockIdx.z;
    const int b = fi/NT, t = fi - b*NT;
    for (int i = tid; i < 768; i += 256){
        int px = i / 12, ck = i % 12;
        *(bf16x8*)(ls + px*104 + ck*8) =
            *(const bf16x8*)(FoT + ((size_t)fi*HWQ + p0 + px)*96 + ck*8);
    }
    __syncthreads();
    for (int i = tid; i < 1536; i += 256){
        int nf = i / 192, rem = i % 192, px = rem / 3, w3 = rem % 3;
        uint2 v = *(const uint2*)(ls + px*104 + nf*12 + w3*4);
        *(uint2*)(FoT2 + (((size_t)((b*8+nf)*NT + t))*HWQ + p0 + px)*12 + w3*4) = v;
    }
}

// ---------- weight prepacks ----------
struct PDDesc { const float* w; unsigned short* pk; int CIN; };
struct PDTable { PDDesc e[4]; };
__global__ void k_prep_dense_all(PDTable tab){
    const PDDesc d = tab.e[blockIdx.y];
    int idx = blockIdx.x*256 + threadIdx.x;
    int total = 9*d.CIN*32;
    if (idx >= total) return;
    int ci = idx & 31;
    int co = (idx >> 5) & 31;
    int kbtap = idx >> 10;
    int KB = d.CIN >> 5;
    int tap = kbtap / KB, kb = kbtap - tap*KB;
    d.pk[idx] = f2bf(d.w[((size_t)co*d.CIN + kb*32 + ci)*9 + tap]);
}

__global__ void k_prep_cf1(const float* __restrict__ w, unsigned short* __restrict__ pk){
    int idx = blockIdx.x*256 + threadIdx.x;
    if (idx >= 9*6*32*32) return;
    int ci = idx & 31;
    int co = (idx >> 5) & 31;
    int tapkb = idx >> 10;
    int tap = tapkb / 6, kb = tapkb - tap*6;
    pk[idx] = (co < 24) ? f2bf(w[((size_t)co*192 + kb*32 + ci)*9 + tap]) : (unsigned short)0;
}

__global__ void k_prep_cf2(const float* __restrict__ w, unsigned short* __restrict__ pk){
    int idx = blockIdx.x*256 + threadIdx.x;
    if (idx >= 9*32*32) return;
    int ci = idx & 31;
    int co = (idx >> 5) & 31;
    int tap = idx >> 10;
    pk[idx] = (co < 24 && ci < 24) ? f2bf(w[((size_t)co*24 + ci)*9 + tap]) : (unsigned short)0;
}

struct P1Desc { const float* w; unsigned short* pk; int Cin; int Cout; };
struct P1Table { P1Desc e[10]; };
__global__ void k_prep_all1x1(P1Table tab){
    const P1Desc d = tab.e[blockIdx.y];
    int idx = blockIdx.x*256 + threadIdx.x;
    if (idx >= (d.Cin>>5)*d.Cout*32) return;
    int ci = idx & 31;
    int co = (idx >> 5) % d.Cout;
    int kb = idx / (d.Cout*32);
    d.pk[idx] = f2bf(d.w[(size_t)co*d.Cin + kb*32 + ci]);
}

// ---------- dense 3x3 conv via MFMA, double-buffered LDS, ONE barrier per kb ----------
template<int KB>
__global__ __launch_bounds__(256) void k_dense_mfma(const unsigned short* __restrict__ catA,
                                                    unsigned short* __restrict__ catB,
                                                    const unsigned short* __restrict__ wpk){
    __shared__ unsigned short ls[2][18*18*40];
    const int tid = threadIdx.x;
    const int wave = tid>>6, lane = tid&63, ln15 = lane&15, lhi = lane>>4;
    const int tile = blockIdx.x;
    const int ty = tile/12, tx = tile - ty*12;
    const int y0 = ty*16, x0 = tx*16;
    const int fi = blockIdx.z;

    f32x4 acc[4][2];
    #pragma unroll
    for (int r=0;r<4;++r){ acc[r][0]=(f32x4)(0.f); acc[r][1]=(f32x4)(0.f); }

    for (int kb=0; kb<KB; ++kb){
        unsigned short* lbuf = ls[kb&1];
        const unsigned short* src;
        int cs;
        if (kb < 3){ src = catA + (size_t)fi*HWQ*96  + kb*32;      cs = 96; }
        else       { src = catB + (size_t)fi*HWQ*128 + (kb-3)*32;  cs = 128; }
        for (int i=tid; i<1296; i+=256){
            int px = i>>2, ck = i&3;
            int iy = px/18, ix = px - iy*18;
            int gy = y0+iy-1, gx = x0+ix-1;
            bf16x8 v = (bf16x8)(short)0;
            if (gy>=0 && gy<HH && gx>=0 && gx<WW)
                v = *(const bf16x8*)(src + ((size_t)(gy*WW+gx))*cs + ck*8);
            *(bf16x8*)(lbuf + (px*40) + ck*8) = v;
        }
        __syncthreads();
        #pragma unroll
        for (int tap=0; tap<9; ++tap){
            const int dy = tap/3 - 1, dxk = tap - (tap/3)*3 - 1;
            const unsigned short* wb = wpk + ((size_t)(tap*KB+kb)*32)*32 + lhi*8;
            bf16x8 b0 = *(const bf16x8*)(wb + ln15*32);
            bf16x8 b1 = *(const bf16x8*)(wb + (16+ln15)*32);
            #pragma unroll
            for (int r=0;r<4;++r){
                const unsigned short* lp = lbuf + ((wave*4+r+dy+1)*18 + (ln15+dxk+1))*40 + lhi*8;
                bf16x8 a = *(const bf16x8*)lp;
                acc[r][0] = __builtin_amdgcn_mfma_f32_16x16x32_bf16(a, b0, acc[r][0], 0,0,0);
                acc[r][1] = __builtin_amdgcn_mfma_f32_16x16x32_bf16(a, b1, acc[r][1], 0,0,0);
            }
        }
    }
    const int coff = (KB-3)*32;
    unsigned short* ob = catB + (size_t)fi*HWQ*128;
    #pragma unroll
    for (int r=0;r<4;++r){
        const int yy = y0 + wave*4 + r;
        #pragma unroll
        for (int ct=0; ct<2; ++ct){
            const int c = coff + ct*16 + ln15;
            #pragma unroll
            for (int q=0;q<4;++q){
                const int xx = x0 + lhi*4 + q;
                ob[((size_t)(yy*WW+xx))*128 + c] = f2bf(lrelu02(acc[r][ct][q]));
            }
        }
    }
}

// final RDB 1x1 (224->96) + bias + residual(catA bf16); fp32 Fo + bf16 FoT
__global__ __launch_bounds__(256) void k_rdbfin_mfma(const unsigned short* __restrict__ catA,
                                                     const unsigned short* __restrict__ catB,
                                                     const unsigned short* __restrict__ pk,
                                                     const float* __restrict__ bias,
                                                     float* __restrict__ Fo,
                                                     unsigned short* __restrict__ FoT){
    const int tid = threadIdx.x;
    const int wave = tid>>6, lane = tid&63, ln15 = lane&15, lhi = lane>>4;
    const int tile = blockIdx.x;
    const int ty = tile/12, tx = tile - ty*12;
    const int y0 = ty*16, x0 = tx*16;
    const int fi = blockIdx.z;
    const int b = fi/NT, t = fi - b*NT;

    f32x4 acc[4][6];
    #pragma unroll
    for (int r=0;r<4;++r)
        #pragma unroll
        for (int ct=0;ct<6;++ct) acc[r][ct]=(f32x4)(0.f);

    for (int kb=0; kb<7; ++kb){
        const unsigned short* src;
        int cs;
        if (kb < 3){ src = catA + (size_t)fi*HWQ*96  + kb*32;      cs = 96; }
        else       { src = catB + (size_t)fi*HWQ*128 + (kb-3)*32;  cs = 128; }
        const unsigned short* wb = pk + ((size_t)kb*96)*32 + lhi*8;
        bf16x8 bfr[6];
        #pragma unroll
        for (int ct=0;ct<6;++ct) bfr[ct] = *(const bf16x8*)(wb + (ct*16+ln15)*32);
        #pragma unroll
        for (int r=0;r<4;++r){
            const int yy = y0 + wave*4 + r;
            const int xx = x0 + ln15;
            bf16x8 a = *(const bf16x8*)(src + ((size_t)(yy*WW+xx))*cs + lhi*8);
            #pragma unroll
            for (int ct=0;ct<6;++ct)
                acc[r][ct] = __builtin_amdgcn_mfma_f32_16x16x32_bf16(a, bfr[ct], acc[r][ct], 0,0,0);
        }
    }
    const unsigned short* resA = catA + (size_t)fi*HWQ*96;
    #pragma unroll
    for (int r=0;r<4;++r){
        const int yy = y0 + wave*4 + r;
        #pragma unroll
        for (int ct=0;ct<6;++ct){
            const int c = ct*16 + ln15;
            #pragma unroll
            for (int q=0;q<4;++q){
                const int xx = x0 + lhi*4 + q;
                float val = acc[r][ct][q] + bias[c] + bf2f(resA[((size_t)(yy*WW+xx))*96 + c]);
                Fo[(((size_t)b*CDIM + c)*NT + t)*HWQ + yy*WW + xx] = val;
                FoT[((size_t)fi*HWQ + yy*WW + xx)*96 + c] = f2bf(val);
            }
        }
    }
}

// ---------- cf1: dbuf LDS, one barrier per kb ----------
__global__ __launch_bounds__(256) void k_cf1_mfma(const unsigned short* __restrict__ F0T,
                                                  const unsigned short* __restrict__ FoT,
                                                  const unsigned short* __restrict__ pk,
                                                  unsigned short* __restrict__ t1T){
    __shared__ unsigned short ls[2][18*18*40];
    const int tid = threadIdx.x;
    const int wave = tid>>6, lane = tid&63, ln15 = lane&15, lhi = lane>>4;
    const int tile = blockIdx.x;
    const int ty = tile/12, tx = tile - ty*12;
    const int y0 = ty*16, x0 = tx*16;
    const int fi = blockIdx.z;
    const int b = fi/NT;
    const unsigned short* srcA = F0T + (size_t)b*HWQ*96;
    const unsigned short* srcB = FoT + (size_t)fi*HWQ*96;

    f32x4 acc[4][2];
    #pragma unroll
    for (int r=0;r<4;++r){ acc[r][0]=(f32x4)(0.f); acc[r][1]=(f32x4)(0.f); }

    for (int kb=0; kb<6; ++kb){
        unsigned short* lbuf = ls[kb&1];
        const unsigned short* src = (kb<3) ? (srcA + kb*32) : (srcB + (kb-3)*32);
        for (int i=tid; i<1296; i+=256){
            int px = i>>2, ck = i&3;
            int iy = px/18, ix = px - iy*18;
            int gy = y0+iy-1, gx = x0+ix-1;
            bf16x8 v = (bf16x8)(short)0;
            if (gy>=0 && gy<HH && gx>=0 && gx<WW)
                v = *(const bf16x8*)(src + ((size_t)(gy*WW+gx))*96 + ck*8);
            *(bf16x8*)(lbuf + (px*40) + ck*8) = v;
        }
        __syncthreads();
        #pragma unroll
        for (int tap=0; tap<9; ++tap){
            const int dy = tap/3 - 1, dxk = tap - (tap/3)*3 - 1;
            const unsigned short* wb = pk + ((size_t)(tap*6+kb)*32)*32 + lhi*8;
            bf16x8 b0 = *(const bf16x8*)(wb + ln15*32);
            bf16x8 b1 = *(const bf16x8*)(wb + (16+ln15)*32);
            #pragma unroll
            for (int r=0;r<4;++r){
                const unsigned short* lp = lbuf + ((wave*4+r+dy+1)*18 + (ln15+dxk+1))*40 + lhi*8;
                bf16x8 a = *(const bf16x8*)lp;
                acc[r][0] = __builtin_amdgcn_mfma_f32_16x16x32_bf16(a, b0, acc[r][0], 0,0,0);
                acc[r][1] = __builtin_amdgcn_mfma_f32_16x16x32_bf16(a, b1, acc[r][1], 0,0,0);
            }
        }
    }
    #pragma unroll
    for (int r=0;r<4;++r){
        const int yy = y0 + wave*4 + r;
        #pragma unroll
        for (int ct=0; ct<2; ++ct){
            const int c = ct*16 + ln15;
            #pragma unroll
            for (int q=0;q<4;++q){
                const int xx = x0 + lhi*4 + q;
                unsigned short v = (c < 24) ? f2bf(lrelu02(acc[r][ct][q])) : (unsigned short)0;
                t1T[((size_t)fi*HWQ + yy*WW + xx)*32 + c] = v;
            }
        }
    }
}

__global__ __launch_bounds__(256) void k_cf2_mfma(const unsigned short* __restrict__ t1T,
                                                  const unsigned short* __restrict__ pk,
                                                  float* __restrict__ fout){
    const int tid = threadIdx.x;
    const int wave = tid>>6, lane = tid&63, ln15 = lane&15, lhi = lane>>4;
    const int tile = blockIdx.x;
    const int ty = tile/12, tx = tile - ty*12;
    const int y0 = ty*16, x0 = tx*16;
    const int fi = blockIdx.z;
    const int b = fi/NT, t = fi - b*NT;
    const unsigned short* src = t1T + (size_t)fi*HWQ*32;

    f32x4 acc[4][2];
    #pragma unroll
    for (int r=0;r<4;++r){ acc[r][0]=(f32x4)(0.f); acc[r][1]=(f32x4)(0.f); }

    #pragma unroll
    for (int tap=0; tap<9; ++tap){
        const int dy = tap/3 - 1, dxk = tap - (tap/3)*3 - 1;
        const unsigned short* wb = pk + ((size_t)tap*32)*32 + lhi*8;
        bf16x8 b0 = *(const bf16x8*)(wb + ln15*32);
        bf16x8 b1 = *(const bf16x8*)(wb + (16+ln15)*32);
        const int xx = x0 + ln15 + dxk;
        const bool okx = (xx>=0) && (xx<WW);
        #pragma unroll
        for (int r=0;r<4;++r){
            const int yy = y0 + wave*4 + r + dy;
            bf16x8 a = (bf16x8)(short)0;
            if (okx && yy>=0 && yy<HH)
                a = *(const bf16x8*)(src + ((size_t)(yy*WW+xx))*32 + lhi*8);
            acc[r][0] = __builtin_amdgcn_mfma_f32_16x16x32_bf16(a, b0, acc[r][0], 0,0,0);
            acc[r][1] = __builtin_amdgcn_mfma_f32_16x16x32_bf16(a, b1, acc[r][1], 0,0,0);
        }
    }
    #pragma unroll
    for (int r=0;r<4;++r){
        const int yy = y0 + wave*4 + r;
        #pragma unroll
        for (int ct=0; ct<2; ++ct){
            const int c = ct*16 + ln15;
            if (c < 24){
                #pragma unroll
                for (int q=0;q<4;++q){
                    const int xx = x0 + lhi*4 + q;
                    fout[(((size_t)b*24 + c)*NT + t)*HWQ + yy*WW + xx] = acc[r][ct][q];
                }
            }
        }
    }
}

// ---------- multiflow backwarp: gathers from nf-major FoT2 [b][nf][t][px][12] ----------
__global__ void k_bwarpcl(const unsigned short* __restrict__ FoT2, const float* __restrict__ fflow,
                          unsigned short* __restrict__ warpedT){
    int p = blockIdx.x*256 + threadIdx.x;
    int y = p/WW, x = p - y*WW;
    int nf = blockIdx.y;          // 0..7
    int b  = blockIdx.z;
    unsigned short* orow = warpedT + ((size_t)b*HWQ + p)*288;
    unsigned short tmp[36] __attribute__((aligned(16)));
    #pragma unroll
    for (int t=0; t<NT; ++t){
        size_t fbi = (((size_t)b*24 + nf*3)*NT + t)*HWQ + p;
        float fx = fflow[fbi];
        float fy = fflow[fbi + (size_t)NT*HWQ];
        float fwv= fflow[fbi + (size_t)2*NT*HWQ];
        float wgt = 1.f/(1.f + expf(-fwv));
        float fxp = (float)x + fx;
        float fyp = (float)y + fy;
        float x0f = floorf(fxp), y0f = floorf(fyp);
        int x0 = (int)x0f, y0 = (int)y0f;
        int x1 = x0+1,    y1 = y0+1;
        float wx1 = fxp - x0f, wy1 = fyp - y0f;
        float wx0 = 1.f - wx1, wy0 = 1.f - wy1;
        bool okx0 = (x0>=0)&&(x0<WW), okx1 = (x1>=0)&&(x1<WW);
        bool oky0 = (y0>=0)&&(y0<HH), oky1 = (y1>=0)&&(y1<HH);
        int xc0 = x0<0?0:(x0>WW-1?WW-1:x0);
        int xc1 = x1<0?0:(x1>WW-1?WW-1:x1);
        int yc0 = y0<0?0:(y0>HH-1?HH-1:y0);
        int yc1 = y1<0?0:(y1>HH-1?HH-1:y1);
        float w00 = wx0*wy0 * ((okx0&&oky0)?1.f:0.f);
        float w10 = wx1*wy0 * ((okx1&&oky0)?1.f:0.f);
        float w01 = wx0*wy1 * ((okx0&&oky1)?1.f:0.f);
        float w11 = wx1*wy1 * ((okx1&&oky1)?1.f:0.f);
        const unsigned short* fo = FoT2 + ((size_t)((b*8+nf)*NT + t))*HWQ*12;
        const unsigned short* r00 = fo + (size_t)(yc0*WW+xc0)*12;
        const unsigned short* r10 = fo + (size_t)(yc0*WW+xc1)*12;
        const unsigned short* r01 = fo + (size_t)(yc1*WW+xc0)*12;
        const unsigned short* r11 = fo + (size_t)(yc1*WW+xc1)*12;
        #pragma unroll
        for (int c=0;c<12;++c){
            float v = w00*bf2f(r00[c]) + w10*bf2f(r10[c]) + w01*bf2f(r01[c]) + w11*bf2f(r11[c]);
            tmp[c*3 + t] = f2bf(v * wgt);
        }
    }
    const uint2* ts = (const uint2*)tmp;
    uint2* td = (uint2*)(orow + nf*36);
    #pragma unroll
    for (int k=0;k<9;++k) td[k] = ts[k];
}

// ---------- generic channels-last 1x1 GEMM via MFMA ----------
template<int KB, int CT, int MODE>
__global__ __launch_bounds__(256) void k_gemm_cl(const unsigned short* __restrict__ inT,
                                                 const unsigned short* __restrict__ pk,
                                                 float* __restrict__ outF,
                                                 unsigned short* __restrict__ outB,
                                                 int Ctot){
    const int tid = threadIdx.x;
    const int wave = tid>>6, lane = tid&63, ln15 = lane&15, lhi = lane>>4;
    const int px0 = blockIdx.x*256 + wave*64;
    const int og  = blockIdx.y;
    const int b   = blockIdx.z;
    const int c0  = og*CT*16;

    f32x4 acc[4][CT];
    #pragma unroll
    for (int r=0;r<4;++r)
        #pragma unroll
        for (int ct=0;ct<CT;++ct) acc[r][ct]=(f32x4)(0.f);

    for (int kb=0; kb<KB; ++kb){
        bf16x8 bfr[CT];
        #pragma unroll
        for (int ct=0;ct<CT;++ct)
            bfr[ct] = *(const bf16x8*)(pk + ((size_t)kb*Ctot + c0 + ct*16 + ln15)*32 + lhi*8);
        #pragma unroll
        for (int r=0;r<4;++r){
            const int px = px0 + r*16 + ln15;
            bf16x8 a = *(const bf16x8*)(inT + ((size_t)b*HWQ + px)*(KB*32) + kb*32 + lhi*8);
            #pragma unroll
            for (int ct=0;ct<CT;++ct)
                acc[r][ct] = __builtin_amdgcn_mfma_f32_16x16x32_bf16(a, bfr[ct], acc[r][ct], 0,0,0);
        }
    }
    #pragma unroll
    for (int r=0;r<4;++r){
        #pragma unroll
        for (int ct=0;ct<CT;++ct){
            const int c = c0 + ct*16 + ln15;
            #pragma unroll
            for (int q=0;q<4;++q){
                const int px = px0 + r*16 + lhi*4 + q;
                size_t o = ((size_t)b*HWQ + px)*Ctot + c;
                if (MODE==0) outF[o] = acc[r][ct][q];
                else if (MODE==1) outF[o] += acc[r][ct][q];
                else outB[o] = f2bf(acc[r][ct][q]);
            }
        }
    }
}

// ---------- layernorm channels-last, LDS-coalesced (4 threads/pixel) ----------
__global__ __launch_bounds__(256) void k_ln_cl(const float* __restrict__ FwC, const float* __restrict__ wln,
                        const float* __restrict__ bln, const float* __restrict__ F0C,
                        unsigned short* __restrict__ xinT){
    __shared__ float ls1[64*100];
    __shared__ float ls3[64*100];
    __shared__ unsigned short ls2[64*104];
    const int tid = threadIdx.x;
    const int p0 = blockIdx.x*64;
    const int b = blockIdx.z;
    for (int i = tid; i < 1536; i += 256){
        int px = i/24, ck = i%24;
        *(f32x4*)(ls1 + px*100 + ck*4) =
            *(const f32x4*)(FwC + ((size_t)b*HWQ + p0 + px)*96 + ck*4);
    }
    if (F0C){
        for (int i = tid; i < 1536; i += 256){
            int px = i/24, ck = i%24;
            *(f32x4*)(ls3 + px*100 + ck*4) =
                *(const f32x4*)(F0C + ((size_t)b*HWQ + p0 + px)*96 + ck*4);
        }
    }
    __syncthreads();
    const int px = tid>>2, sub = tid&3;
    float v[24];
    float s=0.f, ss=0.f;
    #pragma unroll
    for (int k=0;k<24;++k){
        v[k] = ls1[px*100 + sub*24 + k];
        s += v[k]; ss = fmaf(v[k],v[k],ss);
    }
    s  += __shfl_xor(s,1,64);  s  += __shfl_xor(s,2,64);
    ss += __shfl_xor(ss,1,64); ss += __shfl_xor(ss,2,64);
    float mu  = s*(1.f/96.f);
    float var = ss*(1.f/96.f) - mu*mu;
    float rstd = rsqrtf(var + 1e-5f);
    #pragma unroll
    for (int k=0;k<24;++k){
        int c = sub*24 + k;
        float r = (v[k]-mu)*rstd*wln[c] + bln[c];
        if (F0C) r += ls3[px*100 + c];
        ls2[px*104 + c] = f2bf(r);
    }
    __syncthreads();
    for (int i = tid; i < 768; i += 256){
        int px2 = i/12, ck = i%12;
        *(bf16x8*)(xinT + ((size_t)b*HWQ + p0 + px2)*96 + ck*8) =
            *(const bf16x8*)(ls2 + px2*104 + ck*8);
    }
}

// ---------- sliding-window depthwise 3x3, channels-last bf16 ----------
template<int CGIN, int CGOUT, bool GATE>
__global__ __launch_bounds__(256) void k_dw2(const unsigned short* __restrict__ in,
                                             const float* __restrict__ w,
                                             unsigned short* __restrict__ outp){
    __shared__ float lw[GATE ? 576 : 288];
    const int tid = threadIdx.x;
    const int NW = GATE ? 576 : 288;
    for (int i = tid; i < NW; i += 256){
        int st = 0, j = i;
        if (GATE && j >= 288){ st = 1; j -= 288; }
        int cgi = j/72, e = (j%72)/9, tap = j%9;
        int c = (blockIdx.y*4+cgi)*8 + e + (st ? CGOUT*8 : 0);
        lw[i] = w[(size_t)c*9 + tap];
    }
    __syncthreads();
    const int xi = tid & 63, cgi = tid >> 6;
    const int xt = blockIdx.x / 24, ys = blockIdx.x % 24;
    const int x = xt*64 + xi;
    const int y0 = ys*8;
    const int cg = blockIdx.y*4 + cgi;
    const int b = blockIdx.z;
    const unsigned short* ib = in + (size_t)b*HWQ*(CGIN*8) + cg*8;
    unsigned short* ob = outp + (size_t)b*HWQ*(CGOUT*8) + cg*8;
    const float* lw1 = lw + cgi*72;
    const float* lw2 = GATE ? (lw + 288 + cgi*72) : lw;

    const bool okxm = (x-1 >= 0), okxp = (x+1 < WW);
    bf16x8 wA[3][3], wB[3][3];
    #pragma unroll
    for (int s=0;s<3;++s)
        #pragma unroll
        for (int d=0;d<3;++d){ wA[s][d]=(bf16x8)(short)0; if(GATE) wB[s][d]=(bf16x8)(short)0; }

    #pragma unroll
    for (int L=0; L<2; ++L){
        int yy = y0 + L - 1;
        if (yy >= 0){
            const unsigned short* prow = ib + ((size_t)(yy*WW))*(CGIN*8);
            #pragma unroll
            for (int d=0; d<3; ++d){
                int xx = x + d - 1;
                bool ok = (d==0) ? okxm : ((d==2) ? okxp : true);
                if (ok){
                    const unsigned short* p = prow + (size_t)xx*(CGIN*8);
                    wA[L][d] = *(const bf16x8*)p;
                    if (GATE) wB[L][d] = *(const bf16x8*)(p + CGOUT*8);
                }
            }
        }
    }
    #pragma unroll
    for (int yy=0; yy<8; ++yy){
        {
            const int sl = (yy+2)%3;
            int yr = y0 + yy + 1;
            bool oky = (yr < HH);
            #pragma unroll
            for (int d=0; d<3; ++d){
                bf16x8 v = (bf16x8)(short)0, v2 = (bf16x8)(short)0;
                bool ok = oky && ((d==0) ? okxm : ((d==2) ? okxp : true));
                if (ok){
                    const unsigned short* p = ib + ((size_t)(yr*WW + x + d - 1))*(CGIN*8);
                    v = *(const bf16x8*)p;
                    if (GATE) v2 = *(const bf16x8*)(p + CGOUT*8);
                }
                wA[sl][d] = v;
                if (GATE) wB[sl][d] = v2;
            }
        }
        float a1[8], a2[8];
        #pragma unroll
        for (int e=0;e<8;++e){ a1[e]=0.f; a2[e]=0.f; }
        #pragma unroll
        for (int dy=0; dy<3; ++dy){
            const int sl = (yy+dy)%3;
            #pragma unroll
            for (int d=0; d<3; ++d){
                bf16x8 v = wA[sl][d];
                #pragma unroll
                for (int e=0;e<8;++e)
                    a1[e] = fmaf(bf2f((unsigned short)v[e]), lw1[e*9 + dy*3 + d], a1[e]);
                if (GATE){
                    bf16x8 u = wB[sl][d];
                    #pragma unroll
                    for (int e=0;e<8;++e)
                        a2[e] = fmaf(bf2f((unsigned short)u[e]), lw2[e*9 + dy*3 + d], a2[e]);
                }
            }
        }
        bf16x8 o;
        #pragma unroll
        for (int e=0;e<8;++e){
            float r;
            if (GATE){
                float ge = 0.5f*a1[e]*(1.f + erff(a1[e]*0.70710678118654752f));
                r = ge*a2[e];
            } else r = a1[e];
            o[e] = (short)f2bf(r);
        }
        *(bf16x8*)(ob + ((size_t)((y0+yy)*WW + x))*(CGOUT*8)) = o;
    }
}

// ---------- attention stats stage 1 ----------
__global__ __launch_bounds__(256) void k_attnP1(const unsigned short* __restrict__ qkv2T,
                                                float* __restrict__ Spart){
    const int chunk = blockIdx.x;   // 0..15
    const int bh = blockIdx.y;      // 0..15
    const int b = bh>>3, h = bh&7;
    const int tid = threadIdx.x;
    float sq[12], sk[12], S[12][12];
    #pragma unroll
    for (int i=0;i<12;++i){ sq[i]=0.f; sk[i]=0.f;
        #pragma unroll
        for (int j=0;j<12;++j) S[i][j]=0.f; }
    for (int p = chunk*2304 + tid; p < (chunk+1)*2304; p += 256){
        const unsigned short* row = qkv2T + ((size_t)b*HWQ + p)*288;
        float q[12], k[12];
        #pragma unroll
        for (int c=0;c<12;++c){ q[c]=bf2f(row[h*12+c]); k[c]=bf2f(row[96+h*12+c]); }
        #pragma unroll
        for (int c=0;c<12;++c){ sq[c]=fmaf(q[c],q[c],sq[c]); sk[c]=fmaf(k[c],k[c],sk[c]); }
        #pragma unroll
        for (int i=0;i<12;++i)
            #pragma unroll
            for (int j=0;j<12;++j) S[i][j] = fmaf(q[i],k[j],S[i][j]);
    }
    __shared__ float red[4*168];
    const int lane = tid&63, wv = tid>>6;
    #pragma unroll
    for (int c=0;c<12;++c){
        float v = sq[c];
        v += __shfl_down(v,32,64); v += __shfl_down(v,16,64); v += __shfl_down(v,8,64);
        v += __shfl_down(v,4,64);  v += __shfl_down(v,2,64);  v += __shfl_down(v,1,64);
        if (lane==0) red[wv*168 + c] = v;
        float u = sk[c];
        u += __shfl_down(u,32,64); u += __shfl_down(u,16,64); u += __shfl_down(u,8,64);
        u += __shfl_down(u,4,64);  u += __shfl_down(u,2,64);  u += __shfl_down(u,1,64);
        if (lane==0) red[wv*168 + 12 + c] = u;
    }
    #pragma unroll
    for (int i=0;i<12;++i)
        #pragma unroll
        for (int j=0;j<12;++j){
            float v = S[i][j];
            v += __shfl_down(v,32,64); v += __shfl_down(v,16,64); v += __shfl_down(v,8,64);
            v += __shfl_down(v,4,64);  v += __shfl_down(v,2,64);  v += __shfl_down(v,1,64);
            if (lane==0) red[wv*168 + 24 + i*12 + j] = v;
        }
    __syncthreads();
    if (tid < 168){
        float s = red[tid] + red[168+tid] + red[336+tid] + red[504+tid];
        Spart[((size_t)chunk*16 + bh)*168 + tid] = s;
    }
}

// ---------- attention stats stage 2 ----------
__global__ void k_attnP2(const float* __restrict__ Spart, const float* __restrict__ tempp,
                         float* __restrict__ Pbuf){
    int t = threadIdx.x;
    if (t >= 192) return;
    int bh = t/12, i = t - bh*12;
    int h = bh & 7;
    float sqq = 0.f;
    for (int ch=0; ch<16; ++ch) sqq += Spart[((size_t)ch*16+bh)*168 + i];
    float qs = 1.f / fmaxf(sqrtf(sqq), 1e-12f);
    float val[12];
    #pragma unroll
    for (int j=0;j<12;++j){
        float skk = 0.f, sv = 0.f;
        for (int ch=0; ch<16; ++ch){
            skk += Spart[((size_t)ch*16+bh)*168 + 12 + j];
            sv  += Spart[((size_t)ch*16+bh)*168 + 24 + i*12 + j];
        }
        float ks = 1.f / fmaxf(sqrtf(skk), 1e-12f);
        val[j] = sv * qs * ks * tempp[h];
    }
    float mx = val[0];
    #pragma unroll
    for (int j=1;j<12;++j) mx = fmaxf(mx, val[j]);
    float sum = 0.f;
    #pragma unroll
    for (int j=0;j<12;++j){ val[j] = expf(val[j]-mx); sum += val[j]; }
    float inv = 1.f/sum;
    #pragma unroll
    for (int j=0;j<12;++j) Pbuf[(size_t)bh*144 + i*12 + j] = val[j]*inv;
}

// ---------- out = P @ v ----------
__global__ void k_attnV2(const unsigned short* __restrict__ qkv2T, const float* __restrict__ Pbuf,
                         unsigned short* __restrict__ avT){
    __shared__ float P[1152];
    int b = blockIdx.z;
    for (int idx=threadIdx.x; idx<1152; idx+=256) P[idx] = Pbuf[(size_t)b*1152 + idx];
    __syncthreads();
    int p = blockIdx.x*256 + threadIdx.x;
    const unsigned short* row = qkv2T + ((size_t)b*HWQ + p)*288 + 192;
    float v[96];
    #pragma unroll
    for (int c=0;c<96;++c) v[c] = bf2f(row[c]);
    unsigned short* o = avT + ((size_t)b*HWQ + p)*96;
    #pragma unroll
    for (int h=0;h<8;++h){
        #pragma unroll
        for (int i=0;i<12;++i){
            float s = 0.f;
            #pragma unroll
            for (int j=0;j<12;++j) s = fmaf(P[(h*12+i)*12+j], v[h*12+j], s);
            o[h*12+i] = f2bf(s);
        }
    }
}

// ---------- host ----------
extern "C" void kernel_launch(void* const* d_in, const int* in_sizes, int n_in,
                              void* d_out, int out_size, void* d_ws, size_t ws_size,
                              hipStream_t stream){
    const float* F     = (const float*)d_in[0];
    const float* F0c   = (const float*)d_in[1];
    const float* dw0   = (const float*)d_in[2];
    const float* dw1   = (const float*)d_in[3];
    const float* dw2   = (const float*)d_in[4];
    const float* dw3   = (const float*)d_in[5];
    const float* rdbw  = (const float*)d_in[6];
    const float* rdbb  = (const float*)d_in[7];
    const float* cf1w  = (const float*)d_in[8];
    const float* cf2w  = (const float*)d_in[9];
    const float* cFww  = (const float*)d_in[10];
    const float* n1w   = (const float*)d_in[11];
    const float* n1b   = (const float*)d_in[12];
    const float* temp  = (const float*)d_in[13];
    const float* qkvw  = (const float*)d_in[14];
    const float* qkvdw = (const float*)d_in[15];
    const float* projw = (const float*)d_in[16];
    const float* n2w   = (const float*)d_in[17];
    const float* n2b   = (const float*)d_in[18];
    const float* pinw  = (const float*)d_in[19];
    const float* ffndw = (const float*)d_in[20];
    const float* poutw = (const float*)d_in[21];

    float* out = (float*)d_out;
    float* Fo  = out;                    // 2*96*3*HW
    float* Fw  = out + 21233664;         // 2*96*HW
    float* fb  = out + 28311552;         // 2*24*3*HW

    float* ws = (float*)d_ws;
    unsigned short* catA    = (unsigned short*)d_ws;
    unsigned short* catB    = (unsigned short*)(ws + 10616832);
    unsigned short* warpedT = (unsigned short*)d_ws;
    unsigned short* FoT2    = (unsigned short*)(ws + 10616832);
    unsigned short* qkvT    = (unsigned short*)d_ws;
    unsigned short* qkv2T   = (unsigned short*)(ws + 10616832);
    unsigned short* avT     = (unsigned short*)(ws + 21233664);
    unsigned short* ybufT   = (unsigned short*)d_ws;
    unsigned short* gatedT  = (unsigned short*)(ws + 14155776);
    unsigned short* FoT     = (unsigned short*)(ws + 24772608);
    float*          F0C     = ws + 24772608;
    unsigned short* xinT    = (unsigned short*)(ws + 31850496);
    unsigned short* F0T     = (unsigned short*)(ws + 35389440);
    unsigned short* t1T     = (unsigned short*)(ws + 38928384);
    float*          FwC     = ws + 35389440;
    float*          Spart   = ws + 42467328;
    float*          Pbuf    = ws + 42510336;
    unsigned short* P0      = (unsigned short*)(ws + 42512640);
    unsigned short* wpkd  = P0;              // 165888
    unsigned short* rdbpk = P0 + 165888;     // 21504
    unsigned short* cf1pk = P0 + 187392;     // 55296
    unsigned short* cf2pk = P0 + 242688;     // 9216
    unsigned short* cFwpk = P0 + 251904;     // 27648
    unsigned short* qkvpk = P0 + 279552;     // 2*27648
    unsigned short* projpk= P0 + 334848;     // 2*9216
    unsigned short* pinpk = P0 + 353280;     // 2*36864
    unsigned short* poutpk= P0 + 427008;     // 2*18432 -> end 463872

    dim3 blk(256,1,1);

    // layout fills
    k_fillcatT <<<dim3(576,1,6),blk,0,stream>>>(F, catA);
    k_fillF0T  <<<dim3(576,1,2),blk,0,stream>>>(F0c, F0T);
    // dense prepacks in one launch (max total = 9*192*32/256 = 216 blocks)
    {
        PDTable dt;
        dt.e[0] = { dw0, wpkd,                       96 };
        dt.e[1] = { dw1, wpkd+27648,                128 };
        dt.e[2] = { dw2, wpkd+27648+36864,          160 };
        dt.e[3] = { dw3, wpkd+27648+36864+46080,    192 };
        k_prep_dense_all<<<dim3(216,4,1),blk,0,stream>>>(dt);
    }
    k_prep_cf1  <<<dim3(216,1,1),blk,0,stream>>>(cf1w, cf1pk);
    k_prep_cf2  <<<dim3(36,1,1),blk,0,stream>>>(cf2w, cf2pk);
    {
        P1Table tab;
        tab.e[0]  = { rdbw,                      rdbpk,          224,  96 };
        tab.e[1]  = { cFww,                      cFwpk,          288,  96 };
        tab.e[2]  = { qkvw,                      qkvpk,           96, 288 };
        tab.e[3]  = { qkvw + (size_t)288*96,     qkvpk + 27648,   96, 288 };
        tab.e[4]  = { projw,                     projpk,          96,  96 };
        tab.e[5]  = { projw + (size_t)96*96,     projpk + 9216,   96,  96 };
        tab.e[6]  = { pinw,                      pinpk,           96, 384 };
        tab.e[7]  = { pinw + (size_t)384*96,     pinpk + 36864,   96, 384 };
        tab.e[8]  = { poutw,                     poutpk,         192,  96 };
        tab.e[9]  = { poutw + (size_t)96*192,    poutpk + 18432, 192,  96 };
        k_prep_all1x1<<<dim3(144,10,1),blk,0,stream>>>(tab);
    }

    // RDB (bf16 MFMA, dbuf LDS; catA + catB)
    k_dense_mfma<3><<<dim3(144,1,6),blk,0,stream>>>(catA, catB, wpkd);
    k_dense_mfma<4><<<dim3(144,1,6),blk,0,stream>>>(catA, catB, wpkd+27648);
    k_dense_mfma<5><<<dim3(144,1,6),blk,0,stream>>>(catA, catB, wpkd+27648+36864);
    k_dense_mfma<6><<<dim3(144,1,6),blk,0,stream>>>(catA, catB, wpkd+27648+36864+46080);
    k_rdbfin_mfma<<<dim3(144,1,6),blk,0,stream>>>(catA, catB, rdbpk, rdbb, Fo, FoT);

    // flow (bf16 MFMA)
    k_cf1_mfma<<<dim3(144,1,6),blk,0,stream>>>(F0T, FoT, cf1pk, t1T);
    k_cf2_mfma<<<dim3(144,1,6),blk,0,stream>>>(t1T, cf2pk, fb);

    // nf-major split then warp gather
    k_nfsplit<<<dim3(576,1,6),blk,0,stream>>>(FoT, FoT2);
    k_bwarpcl<<<dim3(144,8,2),blk,0,stream>>>(FoT2, fb, warpedT);
    k_packF0C<<<dim3(576,1,2),blk,0,stream>>>(F0c, F0C);
    // convFw
    k_gemm_cl<9,6,0><<<dim3(144,1,2),blk,0,stream>>>(warpedT, cFwpk, FwC, (unsigned short*)0, 96);

    // 2x MAB (channels-last bf16)
    for (int i=0;i<2;++i){
        k_ln_cl<<<dim3(576,1,2),blk,0,stream>>>(FwC, n1w+i*96, n1b+i*96, F0C, xinT);
        k_gemm_cl<3,6,2><<<dim3(144,3,2),blk,0,stream>>>(xinT, qkvpk + i*27648, (float*)0, qkvT, 288);
        k_dw2<36,36,false><<<dim3(72,9,2),blk,0,stream>>>(qkvT, qkvdw + (size_t)i*288*9, qkv2T);
        k_attnP1<<<dim3(16,16,1),blk,0,stream>>>(qkv2T, Spart);
        k_attnP2<<<dim3(1,1,1),blk,0,stream>>>(Spart, temp + i*8, Pbuf);
        k_attnV2<<<dim3(144,1,2),blk,0,stream>>>(qkv2T, Pbuf, avT);
        k_gemm_cl<3,6,1><<<dim3(144,1,2),blk,0,stream>>>(avT, projpk + i*9216, FwC, (unsigned short*)0, 96);

        k_ln_cl<<<dim3(576,1,2),blk,0,stream>>>(FwC, n2w+i*96, n2b+i*96, (const float*)0, xinT);
        k_gemm_cl<3,6,2><<<dim3(144,4,2),blk,0,stream>>>(xinT, pinpk + i*36864, (float*)0, ybufT, 384);
        k_dw2<48,24,true><<<dim3(72,6,2),blk,0,stream>>>(ybufT, ffndw + (size_t)i*384*9, gatedT);
        k_gemm_cl<6,6,1><<<dim3(144,1,2),blk,0,stream>>>(gatedT, poutpk + i*18432, FwC, (unsigned short*)0, 96);
    }

    // unpack FwC -> planar Fw output
    k_unpackFw<<<dim3(576,1,2),blk,0,stream>>>(FwC, Fw);
}

// Round 18
// 1060.554 us; speedup vs baseline: 1.0731x; 1.0731x over previous
//
#include <hip/hip_runtime.h>
#include <math.h>

#define HH 192
#define WW 192
#define HWQ 36864          // 192*192
#define NB 2
#define NT 3
#define CDIM 96

typedef __attribute__((ext_vector_type(8))) short bf16x8;
typedef __attribute__((ext_vector_type(4))) float f32x4;

// ---------- helpers ----------
__device__ __forceinline__ float lrelu02(float v){ return v > 0.f ? v : 0.2f*v; }

__device__ __forceinline__ unsigned short f2bf(float f){
    unsigned u = __builtin_bit_cast(unsigned, f);
    unsigned r = (u + 0x7fff + ((u>>16)&1)) >> 16;   // RNE
    return (unsigned short)r;
}
__device__ __forceinline__ float bf2f(unsigned short u){
    unsigned v = ((unsigned)u)<<16;
    return __builtin_bit_cast(float, v);
}

// ================= layout shims (LDS transpose, coalesced both sides) =================
__global__ __launch_bounds__(256) void k_fillcatT(const float* __restrict__ F,
                                                  unsigned short* __restrict__ catA){
    __shared__ unsigned short ls[64*104];
    const int tid = threadIdx.x;
    const int p0 = blockIdx.x*64;
    const int fi = blockIdx.z;
    const int b = fi/NT, t = fi - b*NT;
    for (int i = tid; i < 6144; i += 256){
        int px = i & 63, c = i >> 6;
        ls[px*104 + c] = f2bf(F[(((size_t)b*CDIM + c)*NT + t)*HWQ + p0 + px]);
    }
    __syncthreads();
    for (int i = tid; i < 768; i += 256){
        int px = i / 12, ck = i % 12;
        *(bf16x8*)(catA + ((size_t)fi*HWQ + p0 + px)*96 + ck*8) =
            *(const bf16x8*)(ls + px*104 + ck*8);
    }
}

__global__ __launch_bounds__(256) void k_fillF0T(const float* __restrict__ F0c,
                                                 unsigned short* __restrict__ F0T){
    __shared__ unsigned short ls[64*104];
    const int tid = threadIdx.x;
    const int p0 = blockIdx.x*64;
    const int b = blockIdx.z;
    for (int i = tid; i < 6144; i += 256){
        int px = i & 63, c = i >> 6;
        ls[px*104 + c] = f2bf(F0c[((size_t)b*96 + c)*HWQ + p0 + px]);
    }
    __syncthreads();
    for (int i = tid; i < 768; i += 256){
        int px = i / 12, ck = i % 12;
        *(bf16x8*)(F0T + ((size_t)b*HWQ + p0 + px)*96 + ck*8) =
            *(const bf16x8*)(ls + px*104 + ck*8);
    }
}

__global__ __launch_bounds__(256) void k_packF0C(const float* __restrict__ F0c,
                                                 float* __restrict__ F0C){
    __shared__ float ls[64*100];
    const int tid = threadIdx.x;
    const int p0 = blockIdx.x*64;
    const int b = blockIdx.z;
    for (int i = tid; i < 6144; i += 256){
        int px = i & 63, c = i >> 6;
        ls[px*100 + c] = F0c[((size_t)b*96 + c)*HWQ + p0 + px];
    }
    __syncthreads();
    for (int i = tid; i < 1536; i += 256){
        int px = i / 24, ck = i % 24;
        *(f32x4*)(F0C + ((size_t)b*HWQ + p0 + px)*96 + ck*4) =
            *(const f32x4*)(ls + px*100 + ck*4);
    }
}

__global__ __launch_bounds__(256) void k_unpackFw(const float* __restrict__ FwC,
                                                  float* __restrict__ Fw){
    __shared__ float ls[64*100];
    const int tid = threadIdx.x;
    const int p0 = blockIdx.x*64;
    const int b = blockIdx.z;
    for (int i = tid; i < 1536; i += 256){
        int px = i / 24, ck = i % 24;
        *(f32x4*)(ls + px*100 + ck*4) =
            *(const f32x4*)(FwC + ((size_t)b*HWQ + p0 + px)*96 + ck*4);
    }
    __syncthreads();
    for (int i = tid; i < 6144; i += 256){
        int px = i & 63, c = i >> 6;
        Fw[((size_t)b*96 + c)*HWQ + p0 + px] = ls[px*100 + c];
    }
}

// FoT [fi][px][96] -> FoT2 [b][nf][t][px][12]
__global__ __launch_bounds__(256) void k_nfsplit(const unsigned short* __restrict__ FoT,
                                                 unsigned short* __restrict__ FoT2){
    __shared__ unsigned short ls[64*104];
    const int tid = threadIdx.x;
    const int p0 = blockIdx.x*64;
    const int fi = blockIdx.z;
    const int b = fi/NT, t = fi - b*NT;
    for (int i = tid; i < 768; i += 256){
        int px = i / 12, ck = i % 12;
        *(bf16x8*)(ls + px*104 + ck*8) =
            *(const bf16x8*)(FoT + ((size_t)fi*HWQ + p0 + px)*96 + ck*8);
    }
    __syncthreads();
    for (int i = tid; i < 1536; i += 256){
        int nf = i / 192, rem = i % 192, px = rem / 3, w3 = rem % 3;
        uint2 v = *(const uint2*)(ls + px*104 + nf*12 + w3*4);
        *(uint2*)(FoT2 + (((size_t)((b*8+nf)*NT + t))*HWQ + p0 + px)*12 + w3*4) = v;
    }
}

// ---------- weight prepacks ----------
struct PDDesc { const float* w; unsigned short* pk; int CIN; };
struct PDTable { PDDesc e[4]; };
__global__ void k_prep_dense_all(PDTable tab){
    const PDDesc d = tab.e[blockIdx.y];
    int idx = blockIdx.x*256 + threadIdx.x;
    int total = 9*d.CIN*32;
    if (idx >= total) return;
    int ci = idx & 31;
    int co = (idx >> 5) & 31;
    int kbtap = idx >> 10;
    int KB = d.CIN >> 5;
    int tap = kbtap / KB, kb = kbtap - tap*KB;
    d.pk[idx] = f2bf(d.w[((size_t)co*d.CIN + kb*32 + ci)*9 + tap]);
}

__global__ void k_prep_cf1(const float* __restrict__ w, unsigned short* __restrict__ pk){
    int idx = blockIdx.x*256 + threadIdx.x;
    if (idx >= 9*6*32*32) return;
    int ci = idx & 31;
    int co = (idx >> 5) & 31;
    int tapkb = idx >> 10;
    int tap = tapkb / 6, kb = tapkb - tap*6;
    pk[idx] = (co < 24) ? f2bf(w[((size_t)co*192 + kb*32 + ci)*9 + tap]) : (unsigned short)0;
}

__global__ void k_prep_cf2(const float* __restrict__ w, unsigned short* __restrict__ pk){
    int idx = blockIdx.x*256 + threadIdx.x;
    if (idx >= 9*32*32) return;
    int ci = idx & 31;
    int co = (idx >> 5) & 31;
    int tap = idx >> 10;
    pk[idx] = (co < 24 && ci < 24) ? f2bf(w[((size_t)co*24 + ci)*9 + tap]) : (unsigned short)0;
}

struct P1Desc { const float* w; unsigned short* pk; int Cin; int Cout; };
struct P1Table { P1Desc e[10]; };
__global__ void k_prep_all1x1(P1Table tab){
    const P1Desc d = tab.e[blockIdx.y];
    int idx = blockIdx.x*256 + threadIdx.x;
    if (idx >= (d.Cin>>5)*d.Cout*32) return;
    int ci = idx & 31;
    int co = (idx >> 5) % d.Cout;
    int kb = idx / (d.Cout*32);
    d.pk[idx] = f2bf(d.w[(size_t)co*d.Cin + kb*32 + ci]);
}

// ---------- dense 3x3 conv via MFMA, LDS-staged (single-buffer, proven best) ----------
template<int KB>
__global__ __launch_bounds__(256) void k_dense_mfma(const unsigned short* __restrict__ catA,
                                                    unsigned short* __restrict__ catB,
                                                    const unsigned short* __restrict__ wpk){
    __shared__ unsigned short ls[18*18*40];
    const int tid = threadIdx.x;
    const int wave = tid>>6, lane = tid&63, ln15 = lane&15, lhi = lane>>4;
    const int tile = blockIdx.x;
    const int ty = tile/12, tx = tile - ty*12;
    const int y0 = ty*16, x0 = tx*16;
    const int fi = blockIdx.z;

    f32x4 acc[4][2];
    #pragma unroll
    for (int r=0;r<4;++r){ acc[r][0]=(f32x4)(0.f); acc[r][1]=(f32x4)(0.f); }

    for (int kb=0; kb<KB; ++kb){
        const unsigned short* src;
        int cs;
        if (kb < 3){ src = catA + (size_t)fi*HWQ*96  + kb*32;      cs = 96; }
        else       { src = catB + (size_t)fi*HWQ*128 + (kb-3)*32;  cs = 128; }
        __syncthreads();
        for (int i=tid; i<1296; i+=256){
            int px = i>>2, ck = i&3;
            int iy = px/18, ix = px - iy*18;
            int gy = y0+iy-1, gx = x0+ix-1;
            bf16x8 v = (bf16x8)(short)0;
            if (gy>=0 && gy<HH && gx>=0 && gx<WW)
                v = *(const bf16x8*)(src + ((size_t)(gy*WW+gx))*cs + ck*8);
            *(bf16x8*)(ls + (px*40) + ck*8) = v;
        }
        __syncthreads();
        #pragma unroll
        for (int tap=0; tap<9; ++tap){
            const int dy = tap/3 - 1, dxk = tap - (tap/3)*3 - 1;
            const unsigned short* wb = wpk + ((size_t)(tap*KB+kb)*32)*32 + lhi*8;
            bf16x8 b0 = *(const bf16x8*)(wb + ln15*32);
            bf16x8 b1 = *(const bf16x8*)(wb + (16+ln15)*32);
            #pragma unroll
            for (int r=0;r<4;++r){
                const unsigned short* lp = ls + ((wave*4+r+dy+1)*18 + (ln15+dxk+1))*40 + lhi*8;
                bf16x8 a = *(const bf16x8*)lp;
                acc[r][0] = __builtin_amdgcn_mfma_f32_16x16x32_bf16(a, b0, acc[r][0], 0,0,0);
                acc[r][1] = __builtin_amdgcn_mfma_f32_16x16x32_bf16(a, b1, acc[r][1], 0,0,0);
            }
        }
    }
    const int coff = (KB-3)*32;
    unsigned short* ob = catB + (size_t)fi*HWQ*128;
    #pragma unroll
    for (int r=0;r<4;++r){
        const int yy = y0 + wave*4 + r;
        #pragma unroll
        for (int ct=0; ct<2; ++ct){
            const int c = coff + ct*16 + ln15;
            #pragma unroll
            for (int q=0;q<4;++q){
                const int xx = x0 + lhi*4 + q;
                ob[((size_t)(yy*WW+xx))*128 + c] = f2bf(lrelu02(acc[r][ct][q]));
            }
        }
    }
}

// final RDB 1x1 (224->96) + bias + residual(catA bf16); fp32 Fo + bf16 FoT
__global__ __launch_bounds__(256) void k_rdbfin_mfma(const unsigned short* __restrict__ catA,
                                                     const unsigned short* __restrict__ catB,
                                                     const unsigned short* __restrict__ pk,
                                                     const float* __restrict__ bias,
                                                     float* __restrict__ Fo,
                                                     unsigned short* __restrict__ FoT){
    const int tid = threadIdx.x;
    const int wave = tid>>6, lane = tid&63, ln15 = lane&15, lhi = lane>>4;
    const int tile = blockIdx.x;
    const int ty = tile/12, tx = tile - ty*12;
    const int y0 = ty*16, x0 = tx*16;
    const int fi = blockIdx.z;
    const int b = fi/NT, t = fi - b*NT;

    f32x4 acc[4][6];
    #pragma unroll
    for (int r=0;r<4;++r)
        #pragma unroll
        for (int ct=0;ct<6;++ct) acc[r][ct]=(f32x4)(0.f);

    for (int kb=0; kb<7; ++kb){
        const unsigned short* src;
        int cs;
        if (kb < 3){ src = catA + (size_t)fi*HWQ*96  + kb*32;      cs = 96; }
        else       { src = catB + (size_t)fi*HWQ*128 + (kb-3)*32;  cs = 128; }
        const unsigned short* wb = pk + ((size_t)kb*96)*32 + lhi*8;
        bf16x8 bfr[6];
        #pragma unroll
        for (int ct=0;ct<6;++ct) bfr[ct] = *(const bf16x8*)(wb + (ct*16+ln15)*32);
        #pragma unroll
        for (int r=0;r<4;++r){
            const int yy = y0 + wave*4 + r;
            const int xx = x0 + ln15;
            bf16x8 a = *(const bf16x8*)(src + ((size_t)(yy*WW+xx))*cs + lhi*8);
            #pragma unroll
            for (int ct=0;ct<6;++ct)
                acc[r][ct] = __builtin_amdgcn_mfma_f32_16x16x32_bf16(a, bfr[ct], acc[r][ct], 0,0,0);
        }
    }
    const unsigned short* resA = catA + (size_t)fi*HWQ*96;
    #pragma unroll
    for (int r=0;r<4;++r){
        const int yy = y0 + wave*4 + r;
        #pragma unroll
        for (int ct=0;ct<6;++ct){
            const int c = ct*16 + ln15;
            #pragma unroll
            for (int q=0;q<4;++q){
                const int xx = x0 + lhi*4 + q;
                float val = acc[r][ct][q] + bias[c] + bf2f(resA[((size_t)(yy*WW+xx))*96 + c]);
                Fo[(((size_t)b*CDIM + c)*NT + t)*HWQ + yy*WW + xx] = val;
                FoT[((size_t)fi*HWQ + yy*WW + xx)*96 + c] = f2bf(val);
            }
        }
    }
}

// ---------- cf1 (single-buffer, proven best) ----------
__global__ __launch_bounds__(256) void k_cf1_mfma(const unsigned short* __restrict__ F0T,
                                                  const unsigned short* __restrict__ FoT,
                                                  const unsigned short* __restrict__ pk,
                                                  unsigned short* __restrict__ t1T){
    __shared__ unsigned short ls[18*18*40];
    const int tid = threadIdx.x;
    const int wave = tid>>6, lane = tid&63, ln15 = lane&15, lhi = lane>>4;
    const int tile = blockIdx.x;
    const int ty = tile/12, tx = tile - ty*12;
    const int y0 = ty*16, x0 = tx*16;
    const int fi = blockIdx.z;
    const int b = fi/NT;
    const unsigned short* srcA = F0T + (size_t)b*HWQ*96;
    const unsigned short* srcB = FoT + (size_t)fi*HWQ*96;

    f32x4 acc[4][2];
    #pragma unroll
    for (int r=0;r<4;++r){ acc[r][0]=(f32x4)(0.f); acc[r][1]=(f32x4)(0.f); }

    for (int kb=0; kb<6; ++kb){
        const unsigned short* src = (kb<3) ? (srcA + kb*32) : (srcB + (kb-3)*32);
        __syncthreads();
        for (int i=tid; i<1296; i+=256){
            int px = i>>2, ck = i&3;
            int iy = px/18, ix = px - iy*18;
            int gy = y0+iy-1, gx = x0+ix-1;
            bf16x8 v = (bf16x8)(short)0;
            if (gy>=0 && gy<HH && gx>=0 && gx<WW)
                v = *(const bf16x8*)(src + ((size_t)(gy*WW+gx))*96 + ck*8);
            *(bf16x8*)(ls + (px*40) + ck*8) = v;
        }
        __syncthreads();
        #pragma unroll
        for (int tap=0; tap<9; ++tap){
            const int dy = tap/3 - 1, dxk = tap - (tap/3)*3 - 1;
            const unsigned short* wb = pk + ((size_t)(tap*6+kb)*32)*32 + lhi*8;
            bf16x8 b0 = *(const bf16x8*)(wb + ln15*32);
            bf16x8 b1 = *(const bf16x8*)(wb + (16+ln15)*32);
            #pragma unroll
            for (int r=0;r<4;++r){
                const unsigned short* lp = ls + ((wave*4+r+dy+1)*18 + (ln15+dxk+1))*40 + lhi*8;
                bf16x8 a = *(const bf16x8*)lp;
                acc[r][0] = __builtin_amdgcn_mfma_f32_16x16x32_bf16(a, b0, acc[r][0], 0,0,0);
                acc[r][1] = __builtin_amdgcn_mfma_f32_16x16x32_bf16(a, b1, acc[r][1], 0,0,0);
            }
        }
    }
    #pragma unroll
    for (int r=0;r<4;++r){
        const int yy = y0 + wave*4 + r;
        #pragma unroll
        for (int ct=0; ct<2; ++ct){
            const int c = ct*16 + ln15;
            #pragma unroll
            for (int q=0;q<4;++q){
                const int xx = x0 + lhi*4 + q;
                unsigned short v = (c < 24) ? f2bf(lrelu02(acc[r][ct][q])) : (unsigned short)0;
                t1T[((size_t)fi*HWQ + yy*WW + xx)*32 + c] = v;
            }
        }
    }
}

__global__ __launch_bounds__(256) void k_cf2_mfma(const unsigned short* __restrict__ t1T,
                                                  const unsigned short* __restrict__ pk,
                                                  float* __restrict__ fout){
    const int tid = threadIdx.x;
    const int wave = tid>>6, lane = tid&63, ln15 = lane&15, lhi = lane>>4;
    const int tile = blockIdx.x;
    const int ty = tile/12, tx = tile - ty*12;
    const int y0 = ty*16, x0 = tx*16;
    const int fi = blockIdx.z;
    const int b = fi/NT, t = fi - b*NT;
    const unsigned short* src = t1T + (size_t)fi*HWQ*32;

    f32x4 acc[4][2];
    #pragma unroll
    for (int r=0;r<4;++r){ acc[r][0]=(f32x4)(0.f); acc[r][1]=(f32x4)(0.f); }

    #pragma unroll
    for (int tap=0; tap<9; ++tap){
        const int dy = tap/3 - 1, dxk = tap - (tap/3)*3 - 1;
        const unsigned short* wb = pk + ((size_t)tap*32)*32 + lhi*8;
        bf16x8 b0 = *(const bf16x8*)(wb + ln15*32);
        bf16x8 b1 = *(const bf16x8*)(wb + (16+ln15)*32);
        const int xx = x0 + ln15 + dxk;
        const bool okx = (xx>=0) && (xx<WW);
        #pragma unroll
        for (int r=0;r<4;++r){
            const int yy = y0 + wave*4 + r + dy;
            bf16x8 a = (bf16x8)(short)0;
            if (okx && yy>=0 && yy<HH)
                a = *(const bf16x8*)(src + ((size_t)(yy*WW+xx))*32 + lhi*8);
            acc[r][0] = __builtin_amdgcn_mfma_f32_16x16x32_bf16(a, b0, acc[r][0], 0,0,0);
            acc[r][1] = __builtin_amdgcn_mfma_f32_16x16x32_bf16(a, b1, acc[r][1], 0,0,0);
        }
    }
    #pragma unroll
    for (int r=0;r<4;++r){
        const int yy = y0 + wave*4 + r;
        #pragma unroll
        for (int ct=0; ct<2; ++ct){
            const int c = ct*16 + ln15;
            if (c < 24){
                #pragma unroll
                for (int q=0;q<4;++q){
                    const int xx = x0 + lhi*4 + q;
                    fout[(((size_t)b*24 + c)*NT + t)*HWQ + yy*WW + xx] = acc[r][ct][q];
                }
            }
        }
    }
}

// ---------- multiflow backwarp: gathers from nf-major FoT2 [b][nf][t][px][12] ----------
__global__ void k_bwarpcl(const unsigned short* __restrict__ FoT2, const float* __restrict__ fflow,
                          unsigned short* __restrict__ warpedT){
    int p = blockIdx.x*256 + threadIdx.x;
    int y = p/WW, x = p - y*WW;
    int nf = blockIdx.y;          // 0..7
    int b  = blockIdx.z;
    unsigned short* orow = warpedT + ((size_t)b*HWQ + p)*288;
    unsigned short tmp[36] __attribute__((aligned(16)));
    #pragma unroll
    for (int t=0; t<NT; ++t){
        size_t fbi = (((size_t)b*24 + nf*3)*NT + t)*HWQ + p;
        float fx = fflow[fbi];
        float fy = fflow[fbi + (size_t)NT*HWQ];
        float fwv= fflow[fbi + (size_t)2*NT*HWQ];
        float wgt = 1.f/(1.f + expf(-fwv));
        float fxp = (float)x + fx;
        float fyp = (float)y + fy;
        float x0f = floorf(fxp), y0f = floorf(fyp);
        int x0 = (int)x0f, y0 = (int)y0f;
        int x1 = x0+1,    y1 = y0+1;
        float wx1 = fxp - x0f, wy1 = fyp - y0f;
        float wx0 = 1.f - wx1, wy0 = 1.f - wy1;
        bool okx0 = (x0>=0)&&(x0<WW), okx1 = (x1>=0)&&(x1<WW);
        bool oky0 = (y0>=0)&&(y0<HH), oky1 = (y1>=0)&&(y1<HH);
        int xc0 = x0<0?0:(x0>WW-1?WW-1:x0);
        int xc1 = x1<0?0:(x1>WW-1?WW-1:x1);
        int yc0 = y0<0?0:(y0>HH-1?HH-1:y0);
        int yc1 = y1<0?0:(y1>HH-1?HH-1:y1);
        float w00 = wx0*wy0 * ((okx0&&oky0)?1.f:0.f);
        float w10 = wx1*wy0 * ((okx1&&oky0)?1.f:0.f);
        float w01 = wx0*wy1 * ((okx0&&oky1)?1.f:0.f);
        float w11 = wx1*wy1 * ((okx1&&oky1)?1.f:0.f);
        const unsigned short* fo = FoT2 + ((size_t)((b*8+nf)*NT + t))*HWQ*12;
        const unsigned short* r00 = fo + (size_t)(yc0*WW+xc0)*12;
        const unsigned short* r10 = fo + (size_t)(yc0*WW+xc1)*12;
        const unsigned short* r01 = fo + (size_t)(yc1*WW+xc0)*12;
        const unsigned short* r11 = fo + (size_t)(yc1*WW+xc1)*12;
        #pragma unroll
        for (int c=0;c<12;++c){
            float v = w00*bf2f(r00[c]) + w10*bf2f(r10[c]) + w01*bf2f(r01[c]) + w11*bf2f(r11[c]);
            tmp[c*3 + t] = f2bf(v * wgt);
        }
    }
    const uint2* ts = (const uint2*)tmp;
    uint2* td = (uint2*)(orow + nf*36);
    #pragma unroll
    for (int k=0;k<9;++k) td[k] = ts[k];
}

// ---------- generic channels-last 1x1 GEMM via MFMA ----------
template<int KB, int CT, int MODE>
__global__ __launch_bounds__(256) void k_gemm_cl(const unsigned short* __restrict__ inT,
                                                 const unsigned short* __restrict__ pk,
                                                 float* __restrict__ outF,
                                                 unsigned short* __restrict__ outB,
                                                 int Ctot){
    const int tid = threadIdx.x;
    const int wave = tid>>6, lane = tid&63, ln15 = lane&15, lhi = lane>>4;
    const int px0 = blockIdx.x*256 + wave*64;
    const int og  = blockIdx.y;
    const int b   = blockIdx.z;
    const int c0  = og*CT*16;

    f32x4 acc[4][CT];
    #pragma unroll
    for (int r=0;r<4;++r)
        #pragma unroll
        for (int ct=0;ct<CT;++ct) acc[r][ct]=(f32x4)(0.f);

    for (int kb=0; kb<KB; ++kb){
        bf16x8 bfr[CT];
        #pragma unroll
        for (int ct=0;ct<CT;++ct)
            bfr[ct] = *(const bf16x8*)(pk + ((size_t)kb*Ctot + c0 + ct*16 + ln15)*32 + lhi*8);
        #pragma unroll
        for (int r=0;r<4;++r){
            const int px = px0 + r*16 + ln15;
            bf16x8 a = *(const bf16x8*)(inT + ((size_t)b*HWQ + px)*(KB*32) + kb*32 + lhi*8);
            #pragma unroll
            for (int ct=0;ct<CT;++ct)
                acc[r][ct] = __builtin_amdgcn_mfma_f32_16x16x32_bf16(a, bfr[ct], acc[r][ct], 0,0,0);
        }
    }
    #pragma unroll
    for (int r=0;r<4;++r){
        #pragma unroll
        for (int ct=0;ct<CT;++ct){
            const int c = c0 + ct*16 + ln15;
            #pragma unroll
            for (int q=0;q<4;++q){
                const int px = px0 + r*16 + lhi*4 + q;
                size_t o = ((size_t)b*HWQ + px)*Ctot + c;
                if (MODE==0) outF[o] = acc[r][ct][q];
                else if (MODE==1) outF[o] += acc[r][ct][q];
                else outB[o] = f2bf(acc[r][ct][q]);
            }
        }
    }
}

// ---------- layernorm channels-last, LDS-coalesced (4 threads/pixel) ----------
__global__ __launch_bounds__(256) void k_ln_cl(const float* __restrict__ FwC, const float* __restrict__ wln,
                        const float* __restrict__ bln, const float* __restrict__ F0C,
                        unsigned short* __restrict__ xinT){
    __shared__ float ls1[64*100];
    __shared__ float ls3[64*100];
    __shared__ unsigned short ls2[64*104];
    const int tid = threadIdx.x;
    const int p0 = blockIdx.x*64;
    const int b = blockIdx.z;
    for (int i = tid; i < 1536; i += 256){
        int px = i/24, ck = i%24;
        *(f32x4*)(ls1 + px*100 + ck*4) =
            *(const f32x4*)(FwC + ((size_t)b*HWQ + p0 + px)*96 + ck*4);
    }
    if (F0C){
        for (int i = tid; i < 1536; i += 256){
            int px = i/24, ck = i%24;
            *(f32x4*)(ls3 + px*100 + ck*4) =
                *(const f32x4*)(F0C + ((size_t)b*HWQ + p0 + px)*96 + ck*4);
        }
    }
    __syncthreads();
    const int px = tid>>2, sub = tid&3;
    float v[24];
    float s=0.f, ss=0.f;
    #pragma unroll
    for (int k=0;k<24;++k){
        v[k] = ls1[px*100 + sub*24 + k];
        s += v[k]; ss = fmaf(v[k],v[k],ss);
    }
    s  += __shfl_xor(s,1,64);  s  += __shfl_xor(s,2,64);
    ss += __shfl_xor(ss,1,64); ss += __shfl_xor(ss,2,64);
    float mu  = s*(1.f/96.f);
    float var = ss*(1.f/96.f) - mu*mu;
    float rstd = rsqrtf(var + 1e-5f);
    #pragma unroll
    for (int k=0;k<24;++k){
        int c = sub*24 + k;
        float r = (v[k]-mu)*rstd*wln[c] + bln[c];
        if (F0C) r += ls3[px*100 + c];
        ls2[px*104 + c] = f2bf(r);
    }
    __syncthreads();
    for (int i = tid; i < 768; i += 256){
        int px2 = i/12, ck = i%12;
        *(bf16x8*)(xinT + ((size_t)b*HWQ + p0 + px2)*96 + ck*8) =
            *(const bf16x8*)(ls2 + px2*104 + ck*8);
    }
}

// ---------- sliding-window depthwise 3x3, channels-last bf16 ----------
template<int CGIN, int CGOUT, bool GATE>
__global__ __launch_bounds__(256) void k_dw2(const unsigned short* __restrict__ in,
                                             const float* __restrict__ w,
                                             unsigned short* __restrict__ outp){
    __shared__ float lw[GATE ? 576 : 288];
    const int tid = threadIdx.x;
    const int NW = GATE ? 576 : 288;
    for (int i = tid; i < NW; i += 256){
        int st = 0, j = i;
        if (GATE && j >= 288){ st = 1; j -= 288; }
        int cgi = j/72, e = (j%72)/9, tap = j%9;
        int c = (blockIdx.y*4+cgi)*8 + e + (st ? CGOUT*8 : 0);
        lw[i] = w[(size_t)c*9 + tap];
    }
    __syncthreads();
    const int xi = tid & 63, cgi = tid >> 6;
    const int xt = blockIdx.x / 24, ys = blockIdx.x % 24;
    const int x = xt*64 + xi;
    const int y0 = ys*8;
    const int cg = blockIdx.y*4 + cgi;
    const int b = blockIdx.z;
    const unsigned short* ib = in + (size_t)b*HWQ*(CGIN*8) + cg*8;
    unsigned short* ob = outp + (size_t)b*HWQ*(CGOUT*8) + cg*8;
    const float* lw1 = lw + cgi*72;
    const float* lw2 = GATE ? (lw + 288 + cgi*72) : lw;

    const bool okxm = (x-1 >= 0), okxp = (x+1 < WW);
    bf16x8 wA[3][3], wB[3][3];
    #pragma unroll
    for (int s=0;s<3;++s)
        #pragma unroll
        for (int d=0;d<3;++d){ wA[s][d]=(bf16x8)(short)0; if(GATE) wB[s][d]=(bf16x8)(short)0; }

    #pragma unroll
    for (int L=0; L<2; ++L){
        int yy = y0 + L - 1;
        if (yy >= 0){
            const unsigned short* prow = ib + ((size_t)(yy*WW))*(CGIN*8);
            #pragma unroll
            for (int d=0; d<3; ++d){
                int xx = x + d - 1;
                bool ok = (d==0) ? okxm : ((d==2) ? okxp : true);
                if (ok){
                    const unsigned short* p = prow + (size_t)xx*(CGIN*8);
                    wA[L][d] = *(const bf16x8*)p;
                    if (GATE) wB[L][d] = *(const bf16x8*)(p + CGOUT*8);
                }
            }
        }
    }
    #pragma unroll
    for (int yy=0; yy<8; ++yy){
        {
            const int sl = (yy+2)%3;
            int yr = y0 + yy + 1;
            bool oky = (yr < HH);
            #pragma unroll
            for (int d=0; d<3; ++d){
                bf16x8 v = (bf16x8)(short)0, v2 = (bf16x8)(short)0;
                bool ok = oky && ((d==0) ? okxm : ((d==2) ? okxp : true));
                if (ok){
                    const unsigned short* p = ib + ((size_t)(yr*WW + x + d - 1))*(CGIN*8);
                    v = *(const bf16x8*)p;
                    if (GATE) v2 = *(const bf16x8*)(p + CGOUT*8);
                }
                wA[sl][d] = v;
                if (GATE) wB[sl][d] = v2;
            }
        }
        float a1[8], a2[8];
        #pragma unroll
        for (int e=0;e<8;++e){ a1[e]=0.f; a2[e]=0.f; }
        #pragma unroll
        for (int dy=0; dy<3; ++dy){
            const int sl = (yy+dy)%3;
            #pragma unroll
            for (int d=0; d<3; ++d){
                bf16x8 v = wA[sl][d];
                #pragma unroll
                for (int e=0;e<8;++e)
                    a1[e] = fmaf(bf2f((unsigned short)v[e]), lw1[e*9 + dy*3 + d], a1[e]);
                if (GATE){
                    bf16x8 u = wB[sl][d];
                    #pragma unroll
                    for (int e=0;e<8;++e)
                        a2[e] = fmaf(bf2f((unsigned short)u[e]), lw2[e*9 + dy*3 + d], a2[e]);
                }
            }
        }
        bf16x8 o;
        #pragma unroll
        for (int e=0;e<8;++e){
            float r;
            if (GATE){
                float ge = 0.5f*a1[e]*(1.f + erff(a1[e]*0.70710678118654752f));
                r = ge*a2[e];
            } else r = a1[e];
            o[e] = (short)f2bf(r);
        }
        *(bf16x8*)(ob + ((size_t)((y0+yy)*WW + x))*(CGOUT*8)) = o;
    }
}

// ---------- attention stats stage 1 ----------
__global__ __launch_bounds__(256) void k_attnP1(const unsigned short* __restrict__ qkv2T,
                                                float* __restrict__ Spart){
    const int chunk = blockIdx.x;   // 0..15
    const int bh = blockIdx.y;      // 0..15
    const int b = bh>>3, h = bh&7;
    const int tid = threadIdx.x;
    float sq[12], sk[12], S[12][12];
    #pragma unroll
    for (int i=0;i<12;++i){ sq[i]=0.f; sk[i]=0.f;
        #pragma unroll
        for (int j=0;j<12;++j) S[i][j]=0.f; }
    for (int p = chunk*2304 + tid; p < (chunk+1)*2304; p += 256){
        const unsigned short* row = qkv2T + ((size_t)b*HWQ + p)*288;
        float q[12], k[12];
        #pragma unroll
        for (int c=0;c<12;++c){ q[c]=bf2f(row[h*12+c]); k[c]=bf2f(row[96+h*12+c]); }
        #pragma unroll
        for (int c=0;c<12;++c){ sq[c]=fmaf(q[c],q[c],sq[c]); sk[c]=fmaf(k[c],k[c],sk[c]); }
        #pragma unroll
        for (int i=0;i<12;++i)
            #pragma unroll
            for (int j=0;j<12;++j) S[i][j] = fmaf(q[i],k[j],S[i][j]);
    }
    __shared__ float red[4*168];
    const int lane = tid&63, wv = tid>>6;
    #pragma unroll
    for (int c=0;c<12;++c){
        float v = sq[c];
        v += __shfl_down(v,32,64); v += __shfl_down(v,16,64); v += __shfl_down(v,8,64);
        v += __shfl_down(v,4,64);  v += __shfl_down(v,2,64);  v += __shfl_down(v,1,64);
        if (lane==0) red[wv*168 + c] = v;
        float u = sk[c];
        u += __shfl_down(u,32,64); u += __shfl_down(u,16,64); u += __shfl_down(u,8,64);
        u += __shfl_down(u,4,64);  u += __shfl_down(u,2,64);  u += __shfl_down(u,1,64);
        if (lane==0) red[wv*168 + 12 + c] = u;
    }
    #pragma unroll
    for (int i=0;i<12;++i)
        #pragma unroll
        for (int j=0;j<12;++j){
            float v = S[i][j];
            v += __shfl_down(v,32,64); v += __shfl_down(v,16,64); v += __shfl_down(v,8,64);
            v += __shfl_down(v,4,64);  v += __shfl_down(v,2,64);  v += __shfl_down(v,1,64);
            if (lane==0) red[wv*168 + 24 + i*12 + j] = v;
        }
    __syncthreads();
    if (tid < 168){
        float s = red[tid] + red[168+tid] + red[336+tid] + red[504+tid];
        Spart[((size_t)chunk*16 + bh)*168 + tid] = s;
    }
}

// ---------- attention stats stage 2 ----------
__global__ void k_attnP2(const float* __restrict__ Spart, const float* __restrict__ tempp,
                         float* __restrict__ Pbuf){
    int t = threadIdx.x;
    if (t >= 192) return;
    int bh = t/12, i = t - bh*12;
    int h = bh & 7;
    float sqq = 0.f;
    for (int ch=0; ch<16; ++ch) sqq += Spart[((size_t)ch*16+bh)*168 + i];
    float qs = 1.f / fmaxf(sqrtf(sqq), 1e-12f);
    float val[12];
    #pragma unroll
    for (int j=0;j<12;++j){
        float skk = 0.f, sv = 0.f;
        for (int ch=0; ch<16; ++ch){
            skk += Spart[((size_t)ch*16+bh)*168 + 12 + j];
            sv  += Spart[((size_t)ch*16+bh)*168 + 24 + i*12 + j];
        }
        float ks = 1.f / fmaxf(sqrtf(skk), 1e-12f);
        val[j] = sv * qs * ks * tempp[h];
    }
    float mx = val[0];
    #pragma unroll
    for (int j=1;j<12;++j) mx = fmaxf(mx, val[j]);
    float sum = 0.f;
    #pragma unroll
    for (int j=0;j<12;++j){ val[j] = expf(val[j]-mx); sum += val[j]; }
    float inv = 1.f/sum;
    #pragma unroll
    for (int j=0;j<12;++j) Pbuf[(size_t)bh*144 + i*12 + j] = val[j]*inv;
}

// ---------- out = P @ v ----------
__global__ void k_attnV2(const unsigned short* __restrict__ qkv2T, const float* __restrict__ Pbuf,
                         unsigned short* __restrict__ avT){
    __shared__ float P[1152];
    int b = blockIdx.z;
    for (int idx=threadIdx.x; idx<1152; idx+=256) P[idx] = Pbuf[(size_t)b*1152 + idx];
    __syncthreads();
    int p = blockIdx.x*256 + threadIdx.x;
    const unsigned short* row = qkv2T + ((size_t)b*HWQ + p)*288 + 192;
    float v[96];
    #pragma unroll
    for (int c=0;c<96;++c) v[c] = bf2f(row[c]);
    unsigned short* o = avT + ((size_t)b*HWQ + p)*96;
    #pragma unroll
    for (int h=0;h<8;++h){
        #pragma unroll
        for (int i=0;i<12;++i){
            float s = 0.f;
            #pragma unroll
            for (int j=0;j<12;++j) s = fmaf(P[(h*12+i)*12+j], v[h*12+j], s);
            o[h*12+i] = f2bf(s);
        }
    }
}

// ---------- host ----------
extern "C" void kernel_launch(void* const* d_in, const int* in_sizes, int n_in,
                              void* d_out, int out_size, void* d_ws, size_t ws_size,
                              hipStream_t stream){
    const float* F     = (const float*)d_in[0];
    const float* F0c   = (const float*)d_in[1];
    const float* dw0   = (const float*)d_in[2];
    const float* dw1   = (const float*)d_in[3];
    const float* dw2   = (const float*)d_in[4];
    const float* dw3   = (const float*)d_in[5];
    const float* rdbw  = (const float*)d_in[6];
    const float* rdbb  = (const float*)d_in[7];
    const float* cf1w  = (const float*)d_in[8];
    const float* cf2w  = (const float*)d_in[9];
    const float* cFww  = (const float*)d_in[10];
    const float* n1w   = (const float*)d_in[11];
    const float* n1b   = (const float*)d_in[12];
    const float* temp  = (const float*)d_in[13];
    const float* qkvw  = (const float*)d_in[14];
    const float* qkvdw = (const float*)d_in[15];
    const float* projw = (const float*)d_in[16];
    const float* n2w   = (const float*)d_in[17];
    const float* n2b   = (const float*)d_in[18];
    const float* pinw  = (const float*)d_in[19];
    const float* ffndw = (const float*)d_in[20];
    const float* poutw = (const float*)d_in[21];

    float* out = (float*)d_out;
    float* Fo  = out;                    // 2*96*3*HW
    float* Fw  = out + 21233664;         // 2*96*HW
    float* fb  = out + 28311552;         // 2*24*3*HW

    float* ws = (float*)d_ws;
    unsigned short* catA    = (unsigned short*)d_ws;
    unsigned short* catB    = (unsigned short*)(ws + 10616832);
    unsigned short* warpedT = (unsigned short*)d_ws;
    unsigned short* FoT2    = (unsigned short*)(ws + 10616832);
    unsigned short* qkvT    = (unsigned short*)d_ws;
    unsigned short* qkv2T   = (unsigned short*)(ws + 10616832);
    unsigned short* avT     = (unsigned short*)(ws + 21233664);
    unsigned short* ybufT   = (unsigned short*)d_ws;
    unsigned short* gatedT  = (unsigned short*)(ws + 14155776);
    unsigned short* FoT     = (unsigned short*)(ws + 24772608);
    float*          F0C     = ws + 24772608;
    unsigned short* xinT    = (unsigned short*)(ws + 31850496);
    unsigned short* F0T     = (unsigned short*)(ws + 35389440);
    unsigned short* t1T     = (unsigned short*)(ws + 38928384);
    float*          FwC     = ws + 35389440;
    float*          Spart   = ws + 42467328;
    float*          Pbuf    = ws + 42510336;
    unsigned short* P0      = (unsigned short*)(ws + 42512640);
    unsigned short* wpkd  = P0;              // 165888
    unsigned short* rdbpk = P0 + 165888;     // 21504
    unsigned short* cf1pk = P0 + 187392;     // 55296
    unsigned short* cf2pk = P0 + 242688;     // 9216
    unsigned short* cFwpk = P0 + 251904;     // 27648
    unsigned short* qkvpk = P0 + 279552;     // 2*27648
    unsigned short* projpk= P0 + 334848;     // 2*9216
    unsigned short* pinpk = P0 + 353280;     // 2*36864
    unsigned short* poutpk= P0 + 427008;     // 2*18432 -> end 463872

    dim3 blk(256,1,1);

    // layout fills
    k_fillcatT <<<dim3(576,1,6),blk,0,stream>>>(F, catA);
    k_fillF0T  <<<dim3(576,1,2),blk,0,stream>>>(F0c, F0T);
    // dense prepacks in one launch
    {
        PDTable dt;
        dt.e[0] = { dw0, wpkd,                       96 };
        dt.e[1] = { dw1, wpkd+27648,                128 };
        dt.e[2] = { dw2, wpkd+27648+36864,          160 };
        dt.e[3] = { dw3, wpkd+27648+36864+46080,    192 };
        k_prep_dense_all<<<dim3(216,4,1),blk,0,stream>>>(dt);
    }
    k_prep_cf1  <<<dim3(216,1,1),blk,0,stream>>>(cf1w, cf1pk);
    k_prep_cf2  <<<dim3(36,1,1),blk,0,stream>>>(cf2w, cf2pk);
    {
        P1Table tab;
        tab.e[0]  = { rdbw,                      rdbpk,          224,  96 };
        tab.e[1]  = { cFww,                      cFwpk,          288,  96 };
        tab.e[2]  = { qkvw,                      qkvpk,           96, 288 };
        tab.e[3]  = { qkvw + (size_t)288*96,     qkvpk + 27648,   96, 288 };
        tab.e[4]  = { projw,                     projpk,          96,  96 };
        tab.e[5]  = { projw + (size_t)96*96,     projpk + 9216,   96,  96 };
        tab.e[6]  = { pinw,                      pinpk,           96, 384 };
        tab.e[7]  = { pinw + (size_t)384*96,     pinpk + 36864,   96, 384 };
        tab.e[8]  = { poutw,                     poutpk,         192,  96 };
        tab.e[9]  = { poutw + (size_t)96*192,    poutpk + 18432, 192,  96 };
        k_prep_all1x1<<<dim3(144,10,1),blk,0,stream>>>(tab);
    }

    // RDB (bf16 MFMA, single-buffer LDS; catA + catB)
    k_dense_mfma<3><<<dim3(144,1,6),blk,0,stream>>>(catA, catB, wpkd);
    k_dense_mfma<4><<<dim3(144,1,6),blk,0,stream>>>(catA, catB, wpkd+27648);
    k_dense_mfma<5><<<dim3(144,1,6),blk,0,stream>>>(catA, catB, wpkd+27648+36864);
    k_dense_mfma<6><<<dim3(144,1,6),blk,0,stream>>>(catA, catB, wpkd+27648+36864+46080);
    k_rdbfin_mfma<<<dim3(144,1,6),blk,0,stream>>>(catA, catB, rdbpk, rdbb, Fo, FoT);

    // flow (bf16 MFMA)
    k_cf1_mfma<<<dim3(144,1,6),blk,0,stream>>>(F0T, FoT, cf1pk, t1T);
    k_cf2_mfma<<<dim3(144,1,6),blk,0,stream>>>(t1T, cf2pk, fb);

    // nf-major split then warp gather
    k_nfsplit<<<dim3(576,1,6),blk,0,stream>>>(FoT, FoT2);
    k_bwarpcl<<<dim3(144,8,2),blk,0,stream>>>(FoT2, fb, warpedT);
    k_packF0C<<<dim3(576,1,2),blk,0,stream>>>(F0c, F0C);
    // convFw
    k_gemm_cl<9,6,0><<<dim3(144,1,2),blk,0,stream>>>(warpedT, cFwpk, FwC, (unsigned short*)0, 96);

    // 2x MAB (channels-last bf16)
    for (int i=0;i<2;++i){
        k_ln_cl<<<dim3(576,1,2),blk,0,stream>>>(FwC, n1w+i*96, n1b+i*96, F0C, xinT);
        k_gemm_cl<3,6,2><<<dim3(144,3,2),blk,0,stream>>>(xinT, qkvpk + i*27648, (float*)0, qkvT, 288);
        k_dw2<36,36,false><<<dim3(72,9,2),blk,0,stream>>>(qkvT, qkvdw + (size_t)i*288*9, qkv2T);
        k_attnP1<<<dim3(16,16,1),blk,0,stream>>>(qkv2T, Spart);
        k_attnP2<<<dim3(1,1,1),blk,0,stream>>>(Spart, temp + i*8, Pbuf);
        k_attnV2<<<dim3(144,1,2),blk,0,stream>>>(qkv2T, Pbuf, avT);
        k_gemm_cl<3,6,1><<<dim3(144,1,2),blk,0,stream>>>(avT, projpk + i*9216, FwC, (unsigned short*)0, 96);

        k_ln_cl<<<dim3(576,1,2),blk,0,stream>>>(FwC, n2w+i*96, n2b+i*96, (const float*)0, xinT);
        k_gemm_cl<3,6,2><<<dim3(144,4,2),blk,0,stream>>>(xinT, pinpk + i*36864, (float*)0, ybufT, 384);
        k_dw2<48,24,true><<<dim3(72,6,2),blk,0,stream>>>(ybufT, ffndw + (size_t)i*384*9, gatedT);
        k_gemm_cl<6,6,1><<<dim3(144,1,2),blk,0,stream>>>(gatedT, poutpk + i*18432, FwC, (unsigned short*)0, 96);
    }

    // unpack FwC -> planar Fw output
    k_unpackFw<<<dim3(576,1,2),blk,0,stream>>>(FwC, Fw);
}

// Round 19
// 1015.720 us; speedup vs baseline: 1.1204x; 1.0441x over previous
//
#include <hip/hip_runtime.h>
#include <math.h>

#define HH 192
#define WW 192
#define HWQ 36864          // 192*192
#define NB 2
#define NT 3
#define CDIM 96

typedef __attribute__((ext_vector_type(8))) short bf16x8;
typedef __attribute__((ext_vector_type(4))) float f32x4;

// ---------- helpers ----------
__device__ __forceinline__ float lrelu02(float v){ return v > 0.f ? v : 0.2f*v; }

__device__ __forceinline__ unsigned short f2bf(float f){
    unsigned u = __builtin_bit_cast(unsigned, f);
    unsigned r = (u + 0x7fff + ((u>>16)&1)) >> 16;   // RNE
    return (unsigned short)r;
}
__device__ __forceinline__ float bf2f(unsigned short u){
    unsigned v = ((unsigned)u)<<16;
    return __builtin_bit_cast(float, v);
}

// ================= layout shims (LDS transpose, coalesced both sides) =================
__global__ __launch_bounds__(256) void k_fillcatT(const float* __restrict__ F,
                                                  unsigned short* __restrict__ catA){
    __shared__ unsigned short ls[64*104];
    const int tid = threadIdx.x;
    const int p0 = blockIdx.x*64;
    const int fi = blockIdx.z;
    const int b = fi/NT, t = fi - b*NT;
    for (int i = tid; i < 6144; i += 256){
        int px = i & 63, c = i >> 6;
        ls[px*104 + c] = f2bf(F[(((size_t)b*CDIM + c)*NT + t)*HWQ + p0 + px]);
    }
    __syncthreads();
    for (int i = tid; i < 768; i += 256){
        int px = i / 12, ck = i % 12;
        *(bf16x8*)(catA + ((size_t)fi*HWQ + p0 + px)*96 + ck*8) =
            *(const bf16x8*)(ls + px*104 + ck*8);
    }
}

// F0c planar fp32 -> BOTH F0T (bf16 CL) and F0C (fp32 CL) in one pass
__global__ __launch_bounds__(256) void k_fillF0both(const float* __restrict__ F0c,
                                                    unsigned short* __restrict__ F0T,
                                                    float* __restrict__ F0C){
    __shared__ float ls[64*100];
    const int tid = threadIdx.x;
    const int p0 = blockIdx.x*64;
    const int b = blockIdx.z;
    for (int i = tid; i < 6144; i += 256){
        int px = i & 63, c = i >> 6;
        ls[px*100 + c] = F0c[((size_t)b*96 + c)*HWQ + p0 + px];
    }
    __syncthreads();
    for (int i = tid; i < 1536; i += 256){
        int px = i / 24, ck = i % 24;
        *(f32x4*)(F0C + ((size_t)b*HWQ + p0 + px)*96 + ck*4) =
            *(const f32x4*)(ls + px*100 + ck*4);
    }
    for (int i = tid; i < 768; i += 256){
        int px = i / 12, ck = i % 12;
        bf16x8 o;
        #pragma unroll
        for (int e=0;e<8;++e) o[e] = (short)f2bf(ls[px*100 + ck*8 + e]);
        *(bf16x8*)(F0T + ((size_t)b*HWQ + p0 + px)*96 + ck*8) = o;
    }
}

__global__ __launch_bounds__(256) void k_unpackFw(const float* __restrict__ FwC,
                                                  float* __restrict__ Fw){
    __shared__ float ls[64*100];
    const int tid = threadIdx.x;
    const int p0 = blockIdx.x*64;
    const int b = blockIdx.z;
    for (int i = tid; i < 1536; i += 256){
        int px = i / 24, ck = i % 24;
        *(f32x4*)(ls + px*100 + ck*4) =
            *(const f32x4*)(FwC + ((size_t)b*HWQ + p0 + px)*96 + ck*4);
    }
    __syncthreads();
    for (int i = tid; i < 6144; i += 256){
        int px = i & 63, c = i >> 6;
        Fw[((size_t)b*96 + c)*HWQ + p0 + px] = ls[px*100 + c];
    }
}

// FoT [fi][px][96] -> FoT2 [b][nf][t][px][12]
__global__ __launch_bounds__(256) void k_nfsplit(const unsigned short* __restrict__ FoT,
                                                 unsigned short* __restrict__ FoT2){
    __shared__ unsigned short ls[64*104];
    const int tid = threadIdx.x;
    const int p0 = blockIdx.x*64;
    const int fi = blockIdx.z;
    const int b = fi/NT, t = fi - b*NT;
    for (int i = tid; i < 768; i += 256){
        int px = i / 12, ck = i % 12;
        *(bf16x8*)(ls + px*104 + ck*8) =
            *(const bf16x8*)(FoT + ((size_t)fi*HWQ + p0 + px)*96 + ck*8);
    }
    __syncthreads();
    for (int i = tid; i < 1536; i += 256){
        int nf = i / 192, rem = i % 192, px = rem / 3, w3 = rem % 3;
        uint2 v = *(const uint2*)(ls + px*104 + nf*12 + w3*4);
        *(uint2*)(FoT2 + (((size_t)((b*8+nf)*NT + t))*HWQ + p0 + px)*12 + w3*4) = v;
    }
}

// ---------- weight prepacks ----------
struct PDDesc { const float* w; unsigned short* pk; int CIN; };
struct PDTable { PDDesc e[4]; };
__global__ void k_prep_dense_all(PDTable tab){
    const PDDesc d = tab.e[blockIdx.y];
    int idx = blockIdx.x*256 + threadIdx.x;
    int total = 9*d.CIN*32;
    if (idx >= total) return;
    int ci = idx & 31;
    int co = (idx >> 5) & 31;
    int kbtap = idx >> 10;
    int KB = d.CIN >> 5;
    int tap = kbtap / KB, kb = kbtap - tap*KB;
    d.pk[idx] = f2bf(d.w[((size_t)co*d.CIN + kb*32 + ci)*9 + tap]);
}

__global__ void k_prep_cf1(const float* __restrict__ w, unsigned short* __restrict__ pk){
    int idx = blockIdx.x*256 + threadIdx.x;
    if (idx >= 9*6*32*32) return;
    int ci = idx & 31;
    int co = (idx >> 5) & 31;
    int tapkb = idx >> 10;
    int tap = tapkb / 6, kb = tapkb - tap*6;
    pk[idx] = (co < 24) ? f2bf(w[((size_t)co*192 + kb*32 + ci)*9 + tap]) : (unsigned short)0;
}

__global__ void k_prep_cf2(const float* __restrict__ w, unsigned short* __restrict__ pk){
    int idx = blockIdx.x*256 + threadIdx.x;
    if (idx >= 9*32*32) return;
    int ci = idx & 31;
    int co = (idx >> 5) & 31;
    int tap = idx >> 10;
    pk[idx] = (co < 24 && ci < 24) ? f2bf(w[((size_t)co*24 + ci)*9 + tap]) : (unsigned short)0;
}

struct P1Desc { const float* w; unsigned short* pk; int Cin; int Cout; };
struct P1Table { P1Desc e[10]; };
__global__ void k_prep_all1x1(P1Table tab){
    const P1Desc d = tab.e[blockIdx.y];
    int idx = blockIdx.x*256 + threadIdx.x;
    if (idx >= (d.Cin>>5)*d.Cout*32) return;
    int ci = idx & 31;
    int co = (idx >> 5) % d.Cout;
    int kb = idx / (d.Cout*32);
    d.pk[idx] = f2bf(d.w[(size_t)co*d.Cin + kb*32 + ci]);
}

// ---------- dense 3x3 conv via MFMA, LDS-staged (single-buffer, proven best) ----------
template<int KB>
__global__ __launch_bounds__(256) void k_dense_mfma(const unsigned short* __restrict__ catA,
                                                    unsigned short* __restrict__ catB,
                                                    const unsigned short* __restrict__ wpk){
    __shared__ unsigned short ls[18*18*40];
    const int tid = threadIdx.x;
    const int wave = tid>>6, lane = tid&63, ln15 = lane&15, lhi = lane>>4;
    const int tile = blockIdx.x;
    const int ty = tile/12, tx = tile - ty*12;
    const int y0 = ty*16, x0 = tx*16;
    const int fi = blockIdx.z;

    f32x4 acc[4][2];
    #pragma unroll
    for (int r=0;r<4;++r){ acc[r][0]=(f32x4)(0.f); acc[r][1]=(f32x4)(0.f); }

    for (int kb=0; kb<KB; ++kb){
        const unsigned short* src;
        int cs;
        if (kb < 3){ src = catA + (size_t)fi*HWQ*96  + kb*32;      cs = 96; }
        else       { src = catB + (size_t)fi*HWQ*128 + (kb-3)*32;  cs = 128; }
        __syncthreads();
        for (int i=tid; i<1296; i+=256){
            int px = i>>2, ck = i&3;
            int iy = px/18, ix = px - iy*18;
            int gy = y0+iy-1, gx = x0+ix-1;
            bf16x8 v = (bf16x8)(short)0;
            if (gy>=0 && gy<HH && gx>=0 && gx<WW)
                v = *(const bf16x8*)(src + ((size_t)(gy*WW+gx))*cs + ck*8);
            *(bf16x8*)(ls + (px*40) + ck*8) = v;
        }
        __syncthreads();
        #pragma unroll
        for (int tap=0; tap<9; ++tap){
            const int dy = tap/3 - 1, dxk = tap - (tap/3)*3 - 1;
            const unsigned short* wb = wpk + ((size_t)(tap*KB+kb)*32)*32 + lhi*8;
            bf16x8 b0 = *(const bf16x8*)(wb + ln15*32);
            bf16x8 b1 = *(const bf16x8*)(wb + (16+ln15)*32);
            #pragma unroll
            for (int r=0;r<4;++r){
                const unsigned short* lp = ls + ((wave*4+r+dy+1)*18 + (ln15+dxk+1))*40 + lhi*8;
                bf16x8 a = *(const bf16x8*)lp;
                acc[r][0] = __builtin_amdgcn_mfma_f32_16x16x32_bf16(a, b0, acc[r][0], 0,0,0);
                acc[r][1] = __builtin_amdgcn_mfma_f32_16x16x32_bf16(a, b1, acc[r][1], 0,0,0);
            }
        }
    }
    const int coff = (KB-3)*32;
    unsigned short* ob = catB + (size_t)fi*HWQ*128;
    #pragma unroll
    for (int r=0;r<4;++r){
        const int yy = y0 + wave*4 + r;
        #pragma unroll
        for (int ct=0; ct<2; ++ct){
            const int c = coff + ct*16 + ln15;
            #pragma unroll
            for (int q=0;q<4;++q){
                const int xx = x0 + lhi*4 + q;
                ob[((size_t)(yy*WW+xx))*128 + c] = f2bf(lrelu02(acc[r][ct][q]));
            }
        }
    }
}

// final RDB 1x1 (224->96) + bias + residual(catA bf16); fp32 Fo + bf16 FoT
__global__ __launch_bounds__(256) void k_rdbfin_mfma(const unsigned short* __restrict__ catA,
                                                     const unsigned short* __restrict__ catB,
                                                     const unsigned short* __restrict__ pk,
                                                     const float* __restrict__ bias,
                                                     float* __restrict__ Fo,
                                                     unsigned short* __restrict__ FoT){
    const int tid = threadIdx.x;
    const int wave = tid>>6, lane = tid&63, ln15 = lane&15, lhi = lane>>4;
    const int tile = blockIdx.x;
    const int ty = tile/12, tx = tile - ty*12;
    const int y0 = ty*16, x0 = tx*16;
    const int fi = blockIdx.z;
    const int b = fi/NT, t = fi - b*NT;

    f32x4 acc[4][6];
    #pragma unroll
    for (int r=0;r<4;++r)
        #pragma unroll
        for (int ct=0;ct<6;++ct) acc[r][ct]=(f32x4)(0.f);

    for (int kb=0; kb<7; ++kb){
        const unsigned short* src;
        int cs;
        if (kb < 3){ src = catA + (size_t)fi*HWQ*96  + kb*32;      cs = 96; }
        else       { src = catB + (size_t)fi*HWQ*128 + (kb-3)*32;  cs = 128; }
        const unsigned short* wb = pk + ((size_t)kb*96)*32 + lhi*8;
        bf16x8 bfr[6];
        #pragma unroll
        for (int ct=0;ct<6;++ct) bfr[ct] = *(const bf16x8*)(wb + (ct*16+ln15)*32);
        #pragma unroll
        for (int r=0;r<4;++r){
            const int yy = y0 + wave*4 + r;
            const int xx = x0 + ln15;
            bf16x8 a = *(const bf16x8*)(src + ((size_t)(yy*WW+xx))*cs + lhi*8);
            #pragma unroll
            for (int ct=0;ct<6;++ct)
                acc[r][ct] = __builtin_amdgcn_mfma_f32_16x16x32_bf16(a, bfr[ct], acc[r][ct], 0,0,0);
        }
    }
    const unsigned short* resA = catA + (size_t)fi*HWQ*96;
    #pragma unroll
    for (int r=0;r<4;++r){
        const int yy = y0 + wave*4 + r;
        #pragma unroll
        for (int ct=0;ct<6;++ct){
            const int c = ct*16 + ln15;
            #pragma unroll
            for (int q=0;q<4;++q){
                const int xx = x0 + lhi*4 + q;
                float val = acc[r][ct][q] + bias[c] + bf2f(resA[((size_t)(yy*WW+xx))*96 + c]);
                Fo[(((size_t)b*CDIM + c)*NT + t)*HWQ + yy*WW + xx] = val;
                FoT[((size_t)fi*HWQ + yy*WW + xx)*96 + c] = f2bf(val);
            }
        }
    }
}

// ---------- cf1 (single-buffer, proven best) ----------
__global__ __launch_bounds__(256) void k_cf1_mfma(const unsigned short* __restrict__ F0T,
                                                  const unsigned short* __restrict__ FoT,
                                                  const unsigned short* __restrict__ pk,
                                                  unsigned short* __restrict__ t1T){
    __shared__ unsigned short ls[18*18*40];
    const int tid = threadIdx.x;
    const int wave = tid>>6, lane = tid&63, ln15 = lane&15, lhi = lane>>4;
    const int tile = blockIdx.x;
    const int ty = tile/12, tx = tile - ty*12;
    const int y0 = ty*16, x0 = tx*16;
    const int fi = blockIdx.z;
    const int b = fi/NT;
    const unsigned short* srcA = F0T + (size_t)b*HWQ*96;
    const unsigned short* srcB = FoT + (size_t)fi*HWQ*96;

    f32x4 acc[4][2];
    #pragma unroll
    for (int r=0;r<4;++r){ acc[r][0]=(f32x4)(0.f); acc[r][1]=(f32x4)(0.f); }

    for (int kb=0; kb<6; ++kb){
        const unsigned short* src = (kb<3) ? (srcA + kb*32) : (srcB + (kb-3)*32);
        __syncthreads();
        for (int i=tid; i<1296; i+=256){
            int px = i>>2, ck = i&3;
            int iy = px/18, ix = px - iy*18;
            int gy = y0+iy-1, gx = x0+ix-1;
            bf16x8 v = (bf16x8)(short)0;
            if (gy>=0 && gy<HH && gx>=0 && gx<WW)
                v = *(const bf16x8*)(src + ((size_t)(gy*WW+gx))*96 + ck*8);
            *(bf16x8*)(ls + (px*40) + ck*8) = v;
        }
        __syncthreads();
        #pragma unroll
        for (int tap=0; tap<9; ++tap){
            const int dy = tap/3 - 1, dxk = tap - (tap/3)*3 - 1;
            const unsigned short* wb = pk + ((size_t)(tap*6+kb)*32)*32 + lhi*8;
            bf16x8 b0 = *(const bf16x8*)(wb + ln15*32);
            bf16x8 b1 = *(const bf16x8*)(wb + (16+ln15)*32);
            #pragma unroll
            for (int r=0;r<4;++r){
                const unsigned short* lp = ls + ((wave*4+r+dy+1)*18 + (ln15+dxk+1))*40 + lhi*8;
                bf16x8 a = *(const bf16x8*)lp;
                acc[r][0] = __builtin_amdgcn_mfma_f32_16x16x32_bf16(a, b0, acc[r][0], 0,0,0);
                acc[r][1] = __builtin_amdgcn_mfma_f32_16x16x32_bf16(a, b1, acc[r][1], 0,0,0);
            }
        }
    }
    #pragma unroll
    for (int r=0;r<4;++r){
        const int yy = y0 + wave*4 + r;
        #pragma unroll
        for (int ct=0; ct<2; ++ct){
            const int c = ct*16 + ln15;
            #pragma unroll
            for (int q=0;q<4;++q){
                const int xx = x0 + lhi*4 + q;
                unsigned short v = (c < 24) ? f2bf(lrelu02(acc[r][ct][q])) : (unsigned short)0;
                t1T[((size_t)fi*HWQ + yy*WW + xx)*32 + c] = v;
            }
        }
    }
}

__global__ __launch_bounds__(256) void k_cf2_mfma(const unsigned short* __restrict__ t1T,
                                                  const unsigned short* __restrict__ pk,
                                                  float* __restrict__ fout){
    const int tid = threadIdx.x;
    const int wave = tid>>6, lane = tid&63, ln15 = lane&15, lhi = lane>>4;
    const int tile = blockIdx.x;
    const int ty = tile/12, tx = tile - ty*12;
    const int y0 = ty*16, x0 = tx*16;
    const int fi = blockIdx.z;
    const int b = fi/NT, t = fi - b*NT;
    const unsigned short* src = t1T + (size_t)fi*HWQ*32;

    f32x4 acc[4][2];
    #pragma unroll
    for (int r=0;r<4;++r){ acc[r][0]=(f32x4)(0.f); acc[r][1]=(f32x4)(0.f); }

    #pragma unroll
    for (int tap=0; tap<9; ++tap){
        const int dy = tap/3 - 1, dxk = tap - (tap/3)*3 - 1;
        const unsigned short* wb = pk + ((size_t)tap*32)*32 + lhi*8;
        bf16x8 b0 = *(const bf16x8*)(wb + ln15*32);
        bf16x8 b1 = *(const bf16x8*)(wb + (16+ln15)*32);
        const int xx = x0 + ln15 + dxk;
        const bool okx = (xx>=0) && (xx<WW);
        #pragma unroll
        for (int r=0;r<4;++r){
            const int yy = y0 + wave*4 + r + dy;
            bf16x8 a = (bf16x8)(short)0;
            if (okx && yy>=0 && yy<HH)
                a = *(const bf16x8*)(src + ((size_t)(yy*WW+xx))*32 + lhi*8);
            acc[r][0] = __builtin_amdgcn_mfma_f32_16x16x32_bf16(a, b0, acc[r][0], 0,0,0);
            acc[r][1] = __builtin_amdgcn_mfma_f32_16x16x32_bf16(a, b1, acc[r][1], 0,0,0);
        }
    }
    #pragma unroll
    for (int r=0;r<4;++r){
        const int yy = y0 + wave*4 + r;
        #pragma unroll
        for (int ct=0; ct<2; ++ct){
            const int c = ct*16 + ln15;
            if (c < 24){
                #pragma unroll
                for (int q=0;q<4;++q){
                    const int xx = x0 + lhi*4 + q;
                    fout[(((size_t)b*24 + c)*NT + t)*HWQ + yy*WW + xx] = acc[r][ct][q];
                }
            }
        }
    }
}

// ---------- multiflow backwarp: gathers from nf-major FoT2 [b][nf][t][px][12] ----------
__global__ void k_bwarpcl(const unsigned short* __restrict__ FoT2, const float* __restrict__ fflow,
                          unsigned short* __restrict__ warpedT){
    int p = blockIdx.x*256 + threadIdx.x;
    int y = p/WW, x = p - y*WW;
    int nf = blockIdx.y;          // 0..7
    int b  = blockIdx.z;
    unsigned short* orow = warpedT + ((size_t)b*HWQ + p)*288;
    unsigned short tmp[36] __attribute__((aligned(16)));
    #pragma unroll
    for (int t=0; t<NT; ++t){
        size_t fbi = (((size_t)b*24 + nf*3)*NT + t)*HWQ + p;
        float fx = fflow[fbi];
        float fy = fflow[fbi + (size_t)NT*HWQ];
        float fwv= fflow[fbi + (size_t)2*NT*HWQ];
        float wgt = 1.f/(1.f + expf(-fwv));
        float fxp = (float)x + fx;
        float fyp = (float)y + fy;
        float x0f = floorf(fxp), y0f = floorf(fyp);
        int x0 = (int)x0f, y0 = (int)y0f;
        int x1 = x0+1,    y1 = y0+1;
        float wx1 = fxp - x0f, wy1 = fyp - y0f;
        float wx0 = 1.f - wx1, wy0 = 1.f - wy1;
        bool okx0 = (x0>=0)&&(x0<WW), okx1 = (x1>=0)&&(x1<WW);
        bool oky0 = (y0>=0)&&(y0<HH), oky1 = (y1>=0)&&(y1<HH);
        int xc0 = x0<0?0:(x0>WW-1?WW-1:x0);
        int xc1 = x1<0?0:(x1>WW-1?WW-1:x1);
        int yc0 = y0<0?0:(y0>HH-1?HH-1:y0);
        int yc1 = y1<0?0:(y1>HH-1?HH-1:y1);
        float w00 = wx0*wy0 * ((okx0&&oky0)?1.f:0.f);
        float w10 = wx1*wy0 * ((okx1&&oky0)?1.f:0.f);
        float w01 = wx0*wy1 * ((okx0&&oky1)?1.f:0.f);
        float w11 = wx1*wy1 * ((okx1&&oky1)?1.f:0.f);
        const unsigned short* fo = FoT2 + ((size_t)((b*8+nf)*NT + t))*HWQ*12;
        const unsigned short* r00 = fo + (size_t)(yc0*WW+xc0)*12;
        const unsigned short* r10 = fo + (size_t)(yc0*WW+xc1)*12;
        const unsigned short* r01 = fo + (size_t)(yc1*WW+xc0)*12;
        const unsigned short* r11 = fo + (size_t)(yc1*WW+xc1)*12;
        #pragma unroll
        for (int c=0;c<12;++c){
            float v = w00*bf2f(r00[c]) + w10*bf2f(r10[c]) + w01*bf2f(r01[c]) + w11*bf2f(r11[c]);
            tmp[c*3 + t] = f2bf(v * wgt);
        }
    }
    const uint2* ts = (const uint2*)tmp;
    uint2* td = (uint2*)(orow + nf*36);
    #pragma unroll
    for (int k=0;k<9;++k) td[k] = ts[k];
}

// ---------- generic channels-last 1x1 GEMM via MFMA; R rows (16px) per wave ----------
template<int KB, int CT, int MODE, int R>
__global__ __launch_bounds__(256) void k_gemm_cl(const unsigned short* __restrict__ inT,
                                                 const unsigned short* __restrict__ pk,
                                                 float* __restrict__ outF,
                                                 unsigned short* __restrict__ outB,
                                                 int Ctot){
    const int tid = threadIdx.x;
    const int wave = tid>>6, lane = tid&63, ln15 = lane&15, lhi = lane>>4;
    const int px0 = blockIdx.x*(R*64) + wave*(R*16);
    const int og  = blockIdx.y;
    const int b   = blockIdx.z;
    const int c0  = og*CT*16;

    f32x4 acc[R][CT];
    #pragma unroll
    for (int r=0;r<R;++r)
        #pragma unroll
        for (int ct=0;ct<CT;++ct) acc[r][ct]=(f32x4)(0.f);

    for (int kb=0; kb<KB; ++kb){
        bf16x8 bfr[CT];
        #pragma unroll
        for (int ct=0;ct<CT;++ct)
            bfr[ct] = *(const bf16x8*)(pk + ((size_t)kb*Ctot + c0 + ct*16 + ln15)*32 + lhi*8);
        #pragma unroll
        for (int r=0;r<R;++r){
            const int px = px0 + r*16 + ln15;
            bf16x8 a = *(const bf16x8*)(inT + ((size_t)b*HWQ + px)*(KB*32) + kb*32 + lhi*8);
            #pragma unroll
            for (int ct=0;ct<CT;++ct)
                acc[r][ct] = __builtin_amdgcn_mfma_f32_16x16x32_bf16(a, bfr[ct], acc[r][ct], 0,0,0);
        }
    }
    #pragma unroll
    for (int r=0;r<R;++r){
        #pragma unroll
        for (int ct=0;ct<CT;++ct){
            const int c = c0 + ct*16 + ln15;
            #pragma unroll
            for (int q=0;q<4;++q){
                const int px = px0 + r*16 + lhi*4 + q;
                size_t o = ((size_t)b*HWQ + px)*Ctot + c;
                if (MODE==0) outF[o] = acc[r][ct][q];
                else if (MODE==1) outF[o] += acc[r][ct][q];
                else outB[o] = f2bf(acc[r][ct][q]);
            }
        }
    }
}

// ---------- layernorm channels-last, LDS-coalesced (4 threads/pixel) ----------
__global__ __launch_bounds__(256) void k_ln_cl(const float* __restrict__ FwC, const float* __restrict__ wln,
                        const float* __restrict__ bln, const float* __restrict__ F0C,
                        unsigned short* __restrict__ xinT){
    __shared__ float ls1[64*100];
    __shared__ float ls3[64*100];
    __shared__ unsigned short ls2[64*104];
    const int tid = threadIdx.x;
    const int p0 = blockIdx.x*64;
    const int b = blockIdx.z;
    for (int i = tid; i < 1536; i += 256){
        int px = i/24, ck = i%24;
        *(f32x4*)(ls1 + px*100 + ck*4) =
            *(const f32x4*)(FwC + ((size_t)b*HWQ + p0 + px)*96 + ck*4);
    }
    if (F0C){
        for (int i = tid; i < 1536; i += 256){
            int px = i/24, ck = i%24;
            *(f32x4*)(ls3 + px*100 + ck*4) =
                *(const f32x4*)(F0C + ((size_t)b*HWQ + p0 + px)*96 + ck*4);
        }
    }
    __syncthreads();
    const int px = tid>>2, sub = tid&3;
    float v[24];
    float s=0.f, ss=0.f;
    #pragma unroll
    for (int k=0;k<24;++k){
        v[k] = ls1[px*100 + sub*24 + k];
        s += v[k]; ss = fmaf(v[k],v[k],ss);
    }
    s  += __shfl_xor(s,1,64);  s  += __shfl_xor(s,2,64);
    ss += __shfl_xor(ss,1,64); ss += __shfl_xor(ss,2,64);
    float mu  = s*(1.f/96.f);
    float var = ss*(1.f/96.f) - mu*mu;
    float rstd = rsqrtf(var + 1e-5f);
    #pragma unroll
    for (int k=0;k<24;++k){
        int c = sub*24 + k;
        float r = (v[k]-mu)*rstd*wln[c] + bln[c];
        if (F0C) r += ls3[px*100 + c];
        ls2[px*104 + c] = f2bf(r);
    }
    __syncthreads();
    for (int i = tid; i < 768; i += 256){
        int px2 = i/12, ck = i%12;
        *(bf16x8*)(xinT + ((size_t)b*HWQ + p0 + px2)*96 + ck*8) =
            *(const bf16x8*)(ls2 + px2*104 + ck*8);
    }
}

// ---------- sliding-window depthwise 3x3, channels-last bf16 ----------
template<int CGIN, int CGOUT, bool GATE>
__global__ __launch_bounds__(256) void k_dw2(const unsigned short* __restrict__ in,
                                             const float* __restrict__ w,
                                             unsigned short* __restrict__ outp){
    __shared__ float lw[GATE ? 576 : 288];
    const int tid = threadIdx.x;
    const int NW = GATE ? 576 : 288;
    for (int i = tid; i < NW; i += 256){
        int st = 0, j = i;
        if (GATE && j >= 288){ st = 1; j -= 288; }
        int cgi = j/72, e = (j%72)/9, tap = j%9;
        int c = (blockIdx.y*4+cgi)*8 + e + (st ? CGOUT*8 : 0);
        lw[i] = w[(size_t)c*9 + tap];
    }
    __syncthreads();
    const int xi = tid & 63, cgi = tid >> 6;
    const int xt = blockIdx.x / 24, ys = blockIdx.x % 24;
    const int x = xt*64 + xi;
    const int y0 = ys*8;
    const int cg = blockIdx.y*4 + cgi;
    const int b = blockIdx.z;
    const unsigned short* ib = in + (size_t)b*HWQ*(CGIN*8) + cg*8;
    unsigned short* ob = outp + (size_t)b*HWQ*(CGOUT*8) + cg*8;
    const float* lw1 = lw + cgi*72;
    const float* lw2 = GATE ? (lw + 288 + cgi*72) : lw;

    const bool okxm = (x-1 >= 0), okxp = (x+1 < WW);
    bf16x8 wA[3][3], wB[3][3];
    #pragma unroll
    for (int s=0;s<3;++s)
        #pragma unroll
        for (int d=0;d<3;++d){ wA[s][d]=(bf16x8)(short)0; if(GATE) wB[s][d]=(bf16x8)(short)0; }

    #pragma unroll
    for (int L=0; L<2; ++L){
        int yy = y0 + L - 1;
        if (yy >= 0){
            const unsigned short* prow = ib + ((size_t)(yy*WW))*(CGIN*8);
            #pragma unroll
            for (int d=0; d<3; ++d){
                int xx = x + d - 1;
                bool ok = (d==0) ? okxm : ((d==2) ? okxp : true);
                if (ok){
                    const unsigned short* p = prow + (size_t)xx*(CGIN*8);
                    wA[L][d] = *(const bf16x8*)p;
                    if (GATE) wB[L][d] = *(const bf16x8*)(p + CGOUT*8);
                }
            }
        }
    }
    #pragma unroll
    for (int yy=0; yy<8; ++yy){
        {
            const int sl = (yy+2)%3;
            int yr = y0 + yy + 1;
            bool oky = (yr < HH);
            #pragma unroll
            for (int d=0; d<3; ++d){
                bf16x8 v = (bf16x8)(short)0, v2 = (bf16x8)(short)0;
                bool ok = oky && ((d==0) ? okxm : ((d==2) ? okxp : true));
                if (ok){
                    const unsigned short* p = ib + ((size_t)(yr*WW + x + d - 1))*(CGIN*8);
                    v = *(const bf16x8*)p;
                    if (GATE) v2 = *(const bf16x8*)(p + CGOUT*8);
                }
                wA[sl][d] = v;
                if (GATE) wB[sl][d] = v2;
            }
        }
        float a1[8], a2[8];
        #pragma unroll
        for (int e=0;e<8;++e){ a1[e]=0.f; a2[e]=0.f; }
        #pragma unroll
        for (int dy=0; dy<3; ++dy){
            const int sl = (yy+dy)%3;
            #pragma unroll
            for (int d=0; d<3; ++d){
                bf16x8 v = wA[sl][d];
                #pragma unroll
                for (int e=0;e<8;++e)
                    a1[e] = fmaf(bf2f((unsigned short)v[e]), lw1[e*9 + dy*3 + d], a1[e]);
                if (GATE){
                    bf16x8 u = wB[sl][d];
                    #pragma unroll
                    for (int e=0;e<8;++e)
                        a2[e] = fmaf(bf2f((unsigned short)u[e]), lw2[e*9 + dy*3 + d], a2[e]);
                }
            }
        }
        bf16x8 o;
        #pragma unroll
        for (int e=0;e<8;++e){
            float r;
            if (GATE){
                float ge = 0.5f*a1[e]*(1.f + erff(a1[e]*0.70710678118654752f));
                r = ge*a2[e];
            } else r = a1[e];
            o[e] = (short)f2bf(r);
        }
        *(bf16x8*)(ob + ((size_t)((y0+yy)*WW + x))*(CGOUT*8)) = o;
    }
}

// ---------- attention stats stage 1 ----------
__global__ __launch_bounds__(256) void k_attnP1(const unsigned short* __restrict__ qkv2T,
                                                float* __restrict__ Spart){
    const int chunk = blockIdx.x;   // 0..15
    const int bh = blockIdx.y;      // 0..15
    const int b = bh>>3, h = bh&7;
    const int tid = threadIdx.x;
    float sq[12], sk[12], S[12][12];
    #pragma unroll
    for (int i=0;i<12;++i){ sq[i]=0.f; sk[i]=0.f;
        #pragma unroll
        for (int j=0;j<12;++j) S[i][j]=0.f; }
    for (int p = chunk*2304 + tid; p < (chunk+1)*2304; p += 256){
        const unsigned short* row = qkv2T + ((size_t)b*HWQ + p)*288;
        float q[12], k[12];
        #pragma unroll
        for (int c=0;c<12;++c){ q[c]=bf2f(row[h*12+c]); k[c]=bf2f(row[96+h*12+c]); }
        #pragma unroll
        for (int c=0;c<12;++c){ sq[c]=fmaf(q[c],q[c],sq[c]); sk[c]=fmaf(k[c],k[c],sk[c]); }
        #pragma unroll
        for (int i=0;i<12;++i)
            #pragma unroll
            for (int j=0;j<12;++j) S[i][j] = fmaf(q[i],k[j],S[i][j]);
    }
    __shared__ float red[4*168];
    const int lane = tid&63, wv = tid>>6;
    #pragma unroll
    for (int c=0;c<12;++c){
        float v = sq[c];
        v += __shfl_down(v,32,64); v += __shfl_down(v,16,64); v += __shfl_down(v,8,64);
        v += __shfl_down(v,4,64);  v += __shfl_down(v,2,64);  v += __shfl_down(v,1,64);
        if (lane==0) red[wv*168 + c] = v;
        float u = sk[c];
        u += __shfl_down(u,32,64); u += __shfl_down(u,16,64); u += __shfl_down(u,8,64);
        u += __shfl_down(u,4,64);  u += __shfl_down(u,2,64);  u += __shfl_down(u,1,64);
        if (lane==0) red[wv*168 + 12 + c] = u;
    }
    #pragma unroll
    for (int i=0;i<12;++i)
        #pragma unroll
        for (int j=0;j<12;++j){
            float v = S[i][j];
            v += __shfl_down(v,32,64); v += __shfl_down(v,16,64); v += __shfl_down(v,8,64);
            v += __shfl_down(v,4,64);  v += __shfl_down(v,2,64);  v += __shfl_down(v,1,64);
            if (lane==0) red[wv*168 + 24 + i*12 + j] = v;
        }
    __syncthreads();
    if (tid < 168){
        float s = red[tid] + red[168+tid] + red[336+tid] + red[504+tid];
        Spart[((size_t)chunk*16 + bh)*168 + tid] = s;
    }
}

// ---------- attention stats stage 2 ----------
__global__ void k_attnP2(const float* __restrict__ Spart, const float* __restrict__ tempp,
                         float* __restrict__ Pbuf){
    int t = threadIdx.x;
    if (t >= 192) return;
    int bh = t/12, i = t - bh*12;
    int h = bh & 7;
    float sqq = 0.f;
    for (int ch=0; ch<16; ++ch) sqq += Spart[((size_t)ch*16+bh)*168 + i];
    float qs = 1.f / fmaxf(sqrtf(sqq), 1e-12f);
    float val[12];
    #pragma unroll
    for (int j=0;j<12;++j){
        float skk = 0.f, sv = 0.f;
        for (int ch=0; ch<16; ++ch){
            skk += Spart[((size_t)ch*16+bh)*168 + 12 + j];
            sv  += Spart[((size_t)ch*16+bh)*168 + 24 + i*12 + j];
        }
        float ks = 1.f / fmaxf(sqrtf(skk), 1e-12f);
        val[j] = sv * qs * ks * tempp[h];
    }
    float mx = val[0];
    #pragma unroll
    for (int j=1;j<12;++j) mx = fmaxf(mx, val[j]);
    float sum = 0.f;
    #pragma unroll
    for (int j=0;j<12;++j){ val[j] = expf(val[j]-mx); sum += val[j]; }
    float inv = 1.f/sum;
    #pragma unroll
    for (int j=0;j<12;++j) Pbuf[(size_t)bh*144 + i*12 + j] = val[j]*inv;
}

// ---------- out = P @ v ----------
__global__ void k_attnV2(const unsigned short* __restrict__ qkv2T, const float* __restrict__ Pbuf,
                         unsigned short* __restrict__ avT){
    __shared__ float P[1152];
    int b = blockIdx.z;
    for (int idx=threadIdx.x; idx<1152; idx+=256) P[idx] = Pbuf[(size_t)b*1152 + idx];
    __syncthreads();
    int p = blockIdx.x*256 + threadIdx.x;
    const unsigned short* row = qkv2T + ((size_t)b*HWQ + p)*288 + 192;
    float v[96];
    #pragma unroll
    for (int c=0;c<96;++c) v[c] = bf2f(row[c]);
    unsigned short* o = avT + ((size_t)b*HWQ + p)*96;
    #pragma unroll
    for (int h=0;h<8;++h){
        #pragma unroll
        for (int i=0;i<12;++i){
            float s = 0.f;
            #pragma unroll
            for (int j=0;j<12;++j) s = fmaf(P[(h*12+i)*12+j], v[h*12+j], s);
            o[h*12+i] = f2bf(s);
        }
    }
}

// ---------- host ----------
extern "C" void kernel_launch(void* const* d_in, const int* in_sizes, int n_in,
                              void* d_out, int out_size, void* d_ws, size_t ws_size,
                              hipStream_t stream){
    const float* F     = (const float*)d_in[0];
    const float* F0c   = (const float*)d_in[1];
    const float* dw0   = (const float*)d_in[2];
    const float* dw1   = (const float*)d_in[3];
    const float* dw2   = (const float*)d_in[4];
    const float* dw3   = (const float*)d_in[5];
    const float* rdbw  = (const float*)d_in[6];
    const float* rdbb  = (const float*)d_in[7];
    const float* cf1w  = (const float*)d_in[8];
    const float* cf2w  = (const float*)d_in[9];
    const float* cFww  = (const float*)d_in[10];
    const float* n1w   = (const float*)d_in[11];
    const float* n1b   = (const float*)d_in[12];
    const float* temp  = (const float*)d_in[13];
    const float* qkvw  = (const float*)d_in[14];
    const float* qkvdw = (const float*)d_in[15];
    const float* projw = (const float*)d_in[16];
    const float* n2w   = (const float*)d_in[17];
    const float* n2b   = (const float*)d_in[18];
    const float* pinw  = (const float*)d_in[19];
    const float* ffndw = (const float*)d_in[20];
    const float* poutw = (const float*)d_in[21];

    float* out = (float*)d_out;
    float* Fo  = out;                    // 2*96*3*HW
    float* Fw  = out + 21233664;         // 2*96*HW
    float* fb  = out + 28311552;         // 2*24*3*HW

    float* ws = (float*)d_ws;
    unsigned short* catA    = (unsigned short*)d_ws;
    unsigned short* catB    = (unsigned short*)(ws + 10616832);
    unsigned short* warpedT = (unsigned short*)d_ws;
    unsigned short* FoT2    = (unsigned short*)(ws + 10616832);
    unsigned short* qkvT    = (unsigned short*)d_ws;
    unsigned short* qkv2T   = (unsigned short*)(ws + 10616832);
    unsigned short* avT     = (unsigned short*)(ws + 21233664);
    unsigned short* ybufT   = (unsigned short*)d_ws;
    unsigned short* gatedT  = (unsigned short*)(ws + 14155776);
    unsigned short* FoT     = (unsigned short*)(ws + 24772608);
    unsigned short* xinT    = (unsigned short*)(ws + 31850496);
    unsigned short* F0T     = (unsigned short*)(ws + 35389440);
    unsigned short* t1T     = (unsigned short*)(ws + 38928384);
    float*          FwC     = ws + 35389440;
    float*          Spart   = ws + 42467328;
    float*          Pbuf    = ws + 42510336;
    unsigned short* P0      = (unsigned short*)(ws + 42512640);
    unsigned short* wpkd  = P0;              // 165888
    unsigned short* rdbpk = P0 + 165888;     // 21504
    unsigned short* cf1pk = P0 + 187392;     // 55296
    unsigned short* cf2pk = P0 + 242688;     // 9216
    unsigned short* cFwpk = P0 + 251904;     // 27648
    unsigned short* qkvpk = P0 + 279552;     // 2*27648
    unsigned short* projpk= P0 + 334848;     // 2*9216
    unsigned short* pinpk = P0 + 353280;     // 2*36864
    unsigned short* poutpk= P0 + 427008;     // 2*18432 -> end 463872 sh = 231936 f
    float*          F0C     = ws + 42744576; // fp32 CL [2][HW][96] = 7077888 f -> end 49822464

    dim3 blk(256,1,1);

    // layout fills (F0both: one read of F0c -> both layouts; F0C now in fresh region)
    k_fillcatT <<<dim3(576,1,6),blk,0,stream>>>(F, catA);
    k_fillF0both<<<dim3(576,1,2),blk,0,stream>>>(F0c, F0T, F0C);
    {
        PDTable dt;
        dt.e[0] = { dw0, wpkd,                       96 };
        dt.e[1] = { dw1, wpkd+27648,                128 };
        dt.e[2] = { dw2, wpkd+27648+36864,          160 };
        dt.e[3] = { dw3, wpkd+27648+36864+46080,    192 };
        k_prep_dense_all<<<dim3(216,4,1),blk,0,stream>>>(dt);
    }
    k_prep_cf1  <<<dim3(216,1,1),blk,0,stream>>>(cf1w, cf1pk);
    k_prep_cf2  <<<dim3(36,1,1),blk,0,stream>>>(cf2w, cf2pk);
    {
        P1Table tab;
        tab.e[0]  = { rdbw,                      rdbpk,          224,  96 };
        tab.e[1]  = { cFww,                      cFwpk,          288,  96 };
        tab.e[2]  = { qkvw,                      qkvpk,           96, 288 };
        tab.e[3]  = { qkvw + (size_t)288*96,     qkvpk + 27648,   96, 288 };
        tab.e[4]  = { projw,                     projpk,          96,  96 };
        tab.e[5]  = { projw + (size_t)96*96,     projpk + 9216,   96,  96 };
        tab.e[6]  = { pinw,                      pinpk,           96, 384 };
        tab.e[7]  = { pinw + (size_t)384*96,     pinpk + 36864,   96, 384 };
        tab.e[8]  = { poutw,                     poutpk,         192,  96 };
        tab.e[9]  = { poutw + (size_t)96*192,    poutpk + 18432, 192,  96 };
        k_prep_all1x1<<<dim3(144,10,1),blk,0,stream>>>(tab);
    }

    // RDB (bf16 MFMA, single-buffer LDS; catA + catB)
    k_dense_mfma<3><<<dim3(144,1,6),blk,0,stream>>>(catA, catB, wpkd);
    k_dense_mfma<4><<<dim3(144,1,6),blk,0,stream>>>(catA, catB, wpkd+27648);
    k_dense_mfma<5><<<dim3(144,1,6),blk,0,stream>>>(catA, catB, wpkd+27648+36864);
    k_dense_mfma<6><<<dim3(144,1,6),blk,0,stream>>>(catA, catB, wpkd+27648+36864+46080);
    k_rdbfin_mfma<<<dim3(144,1,6),blk,0,stream>>>(catA, catB, rdbpk, rdbb, Fo, FoT);

    // flow (bf16 MFMA)
    k_cf1_mfma<<<dim3(144,1,6),blk,0,stream>>>(F0T, FoT, cf1pk, t1T);
    k_cf2_mfma<<<dim3(144,1,6),blk,0,stream>>>(t1T, cf2pk, fb);

    // nf-major split then warp gather
    k_nfsplit<<<dim3(576,1,6),blk,0,stream>>>(FoT, FoT2);
    k_bwarpcl<<<dim3(144,8,2),blk,0,stream>>>(FoT2, fb, warpedT);
    // convFw: R=2 (more waves/SIMD)
    k_gemm_cl<9,6,0,2><<<dim3(288,1,2),blk,0,stream>>>(warpedT, cFwpk, FwC, (unsigned short*)0, 96);

    // 2x MAB (channels-last bf16)
    for (int i=0;i<2;++i){
        k_ln_cl<<<dim3(576,1,2),blk,0,stream>>>(FwC, n1w+i*96, n1b+i*96, F0C, xinT);
        k_gemm_cl<3,6,2,4><<<dim3(144,3,2),blk,0,stream>>>(xinT, qkvpk + i*27648, (float*)0, qkvT, 288);
        k_dw2<36,36,false><<<dim3(72,9,2),blk,0,stream>>>(qkvT, qkvdw + (size_t)i*288*9, qkv2T);
        k_attnP1<<<dim3(16,16,1),blk,0,stream>>>(qkv2T, Spart);
        k_attnP2<<<dim3(1,1,1),blk,0,stream>>>(Spart, temp + i*8, Pbuf);
        k_attnV2<<<dim3(144,1,2),blk,0,stream>>>(qkv2T, Pbuf, avT);
        k_gemm_cl<3,6,1,2><<<dim3(288,1,2),blk,0,stream>>>(avT, projpk + i*9216, FwC, (unsigned short*)0, 96);

        k_ln_cl<<<dim3(576,1,2),blk,0,stream>>>(FwC, n2w+i*96, n2b+i*96, (const float*)0, xinT);
        k_gemm_cl<3,6,2,4><<<dim3(144,4,2),blk,0,stream>>>(xinT, pinpk + i*36864, (float*)0, ybufT, 384);
        k_dw2<48,24,true><<<dim3(72,6,2),blk,0,stream>>>(ybufT, ffndw + (size_t)i*384*9, gatedT);
        k_gemm_cl<6,6,1,2><<<dim3(288,1,2),blk,0,stream>>>(gatedT, poutpk + i*18432, FwC, (unsigned short*)0, 96);
    }

    // unpack FwC -> planar Fw output
    k_unpackFw<<<dim3(576,1,2),blk,0,stream>>>(FwC, Fw);
}